// Round 15
// baseline (165.204 us; speedup 1.0000x reference)
//
#include <hip/hip_runtime.h>
#include <hip/hip_bf16.h>

typedef unsigned short u16;
typedef unsigned int u32;
typedef __attribute__((ext_vector_type(8))) short short8;   // 8 bf16 for MFMA frags
typedef __attribute__((ext_vector_type(8))) u16 ushort8;
typedef __attribute__((ext_vector_type(4))) float f32x4;

// ---------- constants ----------
#define BB 2048
#define SS 8
#define DNUM 8
#define LL 50
#define EDIM 16
#define FDIM 512
#define HID1 256
#define HID2 128
#define VF 100000
#define KDNN 1216          // 1160 padded to 64-multiple
#define ROWS (BB*LL)       // 102400

// ---------- helpers ----------
__device__ inline u16 f2bf(float x) {            // HW RNE cvt (compiler packs)
    return __builtin_bit_cast(u16, __float2bfloat16(x));
}
__device__ inline float bf2f(u16 b) {
    u32 u = ((u32)b) << 16;
    return __builtin_bit_cast(float, u);
}
__device__ inline void load16_lds(const void* g, void* l) {
    __builtin_amdgcn_global_load_lds(
        (const __attribute__((address_space(1))) u32*)g,
        (__attribute__((address_space(3))) u32*)l, 16, 0, 0);
}
__device__ inline float wave_sum(float v) {
    #pragma unroll
    for (int off = 32; off > 0; off >>= 1) v += __shfl_xor(v, off, 64);
    return v;
}
__device__ inline float wave_max(float v) {
    #pragma unroll
    for (int off = 32; off > 0; off >>= 1) v = fmaxf(v, __shfl_xor(v, off, 64));
    return v;
}
__device__ inline void cvt8(const float4& a, const float4& b, ushort8& o) {
    o[0]=f2bf(a.x); o[1]=f2bf(a.y); o[2]=f2bf(a.z); o[3]=f2bf(a.w);
    o[4]=f2bf(b.x); o[5]=f2bf(b.y); o[6]=f2bf(b.z); o[7]=f2bf(b.w);
}

// ---------- K-2: zero used-row flags (re-zeroed every call: determinism) ----------
__global__ __launch_bounds__(256) void zero_flags(u32* __restrict__ f) {
    int i = blockIdx.x * 256 + threadIdx.x;
    if (i < 25024) f[i] = 0;          // 100096 bytes
}

// ---------- K-1: mark rows referenced by hist_ids / feedid ----------
__global__ __launch_bounds__(256) void mark_used(
    const int* __restrict__ hist, const int* __restrict__ feedid,
    unsigned char* __restrict__ flags)
{
    int i = blockIdx.x * 256 + threadIdx.x;
    if (i < ROWS) flags[hist[i]] = 1;
    if (i < BB) flags[feedid[i]] = 1;
}

// ---------- K0 (fused): dedup'd cvt + weight prep + per-b gather ----------
#define CVT_BLKS 25000
#define PREP_BLKS 2112
__global__ __launch_bounds__(256) void prep_all(
    const float* __restrict__ ft, u16* __restrict__ hb,
    const unsigned char* __restrict__ flags,
    const float* __restrict__ w1, const float* __restrict__ dw1,
    const float* __restrict__ dw2,
    u16* __restrict__ WHP_T, u16* __restrict__ WQ_T,
    u16* __restrict__ W1D_T, u16* __restrict__ W2D_T,
    const int* __restrict__ sparse_ids, const float* __restrict__ dense,
    const int* __restrict__ feedid, const float* __restrict__ emb_tables,
    u16* __restrict__ dnn_in, u16* __restrict__ A_q)
{
    int blk = blockIdx.x, t = threadIdx.x;
    if (blk < CVT_BLKS) {
        int r = blk * 4 + (t >> 6);
        if (flags[r]) {
            const float* src = ft + (size_t)r * FDIM + (t & 63) * 8;
            float4 a = *(const float4*)src;
            float4 b = *(const float4*)(src + 4);
            ushort8 o; cvt8(a, b, o);
            *(ushort8*)(hb + (size_t)r * FDIM + (t & 63) * 8) = o;
        }
    } else if (blk < CVT_BLKS + PREP_BLKS) {
        int idx = (blk - CVT_BLKS) * 256 + t;
        if (idx < 131072) {
            int n = idx >> 10, k = idx & 1023;
            float v;
            if (k < 512) v = w1[(512 + k) * 128 + n] - w1[(1024 + k) * 128 + n];
            else         v = w1[(1024 + k) * 128 + n];   // 1536 + (k-512)
            WHP_T[n * 1024 + k] = f2bf(v);
        } else if (idx < 196608) {
            int i = idx - 131072;
            int n = i >> 9, k = i & 511;
            WQ_T[n * 512 + k] = f2bf(w1[k * 128 + n] + w1[(1024 + k) * 128 + n]);
        } else if (idx < 507904) {
            int i = idx - 196608;
            int n = i / KDNN, k = i - n * KDNN;
            W1D_T[i] = (k < 1160) ? f2bf(dw1[k * HID1 + n]) : (u16)0;
        } else if (idx < 540672) {
            int i = idx - 507904;
            int n = i >> 8, k = i & 255;
            W2D_T[i] = f2bf(dw2[k * HID2 + n]);
        }
    } else {
        int b = blk - (CVT_BLKS + PREP_BLKS);
        u16* drow = dnn_in + (size_t)b * KDNN;
        if (t < 128) {
            int s = t >> 4, e = t & 15;
            int id = sparse_ids[b * SS + s];
            float v = emb_tables[(size_t)s * 1600000 + (size_t)id * EDIM + e];
            drow[t] = f2bf(v);
        } else if (t < 136) {
            drow[t] = f2bf(dense[b * DNUM + (t - 128)]);
        } else if (t < 192) {
            drow[1160 + (t - 136)] = 0;   // K padding
        }
        int fid = feedid[b];
        float2 f = *(const float2*)&ft[(size_t)fid * FDIM + t * 2];
        u16 u0 = f2bf(f.x), u1 = f2bf(f.y);
        drow[136 + t * 2] = u0;
        drow[136 + t * 2 + 1] = u1;
        A_q[(size_t)b * FDIM + t * 2] = u0;
        A_q[(size_t)b * FDIM + t * 2 + 1] = u1;
    }
}

// ---------- K2: generic bf16 MFMA GEMM, 2-phase pipelined staging ----------
// stage(kt+1) issued BEFORE compute(kt); single __syncthreads per step
// drains loads that had the whole compute phase to land (T3 template).
template<int BM, bool RELU, bool OUT_BF16>
__global__ __launch_bounds__(256, 3) void gemm_bt(
    const u16* __restrict__ A, int lda,
    const u16* __restrict__ BT, int ldb,
    const float* __restrict__ bias,
    void* __restrict__ Cv, int M, int N, int K)
{
    constexpr int MI = BM / 32;           // frags per wave in M
    __shared__ u16 As[2][BM * 64];
    __shared__ u16 Bs[2][128 * 64];
    int m0 = blockIdx.x * BM, n0 = blockIdx.y * 128;
    int tid = threadIdx.x, wave = tid >> 6, lane = tid & 63;
    int lrow = lane >> 3, lk = (lane & 7) * 8;
    f32x4 acc[MI][4];
    f32x4 zz = {0.f, 0.f, 0.f, 0.f};
    #pragma unroll
    for (int i = 0; i < MI; i++)
        #pragma unroll
        for (int j = 0; j < 4; j++) acc[i][j] = zz;
    int wm = (wave >> 1) * (BM / 2), wn = (wave & 1) * 64;

    auto stage = [&](int kt, int buf) {
        #pragma unroll
        for (int j = 0; j < MI; ++j) {
            int c = wave * MI + j;
            int row = c * 8 + lrow;
            load16_lds(A + (size_t)(m0 + row) * lda + kt + lk, &As[buf][c * 512]);
        }
        #pragma unroll
        for (int j = 0; j < 4; ++j) {
            int c = wave * 4 + j;
            int row = c * 8 + lrow;
            load16_lds(BT + (size_t)(n0 + row) * ldb + kt + lk, &Bs[buf][c * 512]);
        }
    };

    stage(0, 0);
    __syncthreads();
    int nsteps = K / 64;
    for (int s_ = 0; s_ < nsteps; ++s_) {
        int buf = s_ & 1;
        if (s_ + 1 < nsteps) stage((s_ + 1) * 64, buf ^ 1);
        #pragma unroll
        for (int ks = 0; ks < 2; ++ks) {
            int kk = ks * 32 + (lane >> 4) * 8;
            short8 af[MI], bf[4];
            #pragma unroll
            for (int i = 0; i < MI; i++)
                af[i] = *(const short8*)&As[buf][(wm + i * 16 + (lane & 15)) * 64 + kk];
            #pragma unroll
            for (int j = 0; j < 4; j++)
                bf[j] = *(const short8*)&Bs[buf][(wn + j * 16 + (lane & 15)) * 64 + kk];
            #pragma unroll
            for (int i = 0; i < MI; i++)
                #pragma unroll
                for (int j = 0; j < 4; j++)
                    acc[i][j] = __builtin_amdgcn_mfma_f32_16x16x32_bf16(
                        af[i], bf[j], acc[i][j], 0, 0, 0);
        }
        __syncthreads();
    }
    #pragma unroll
    for (int i = 0; i < MI; i++) {
        #pragma unroll
        for (int j = 0; j < 4; j++) {
            #pragma unroll
            for (int r = 0; r < 4; r++) {
                int row = m0 + wm + i * 16 + (lane >> 4) * 4 + r;
                int col = n0 + wn + j * 16 + (lane & 15);
                float v = acc[i][j][r];
                if (bias) v += bias[col];
                if (RELU) v = fmaxf(v, 0.f);
                size_t off = (size_t)row * N + col;
                if (OUT_BF16) ((u16*)Cv)[off] = f2bf(v);
                else ((float*)Cv)[off] = v;
            }
        }
    }
}

#define MFMA_BF16 __builtin_amdgcn_mfma_f32_16x16x32_bf16

// ---------- K3: DIN GEMM v16 — gathered global_load_lds + 2-phase pipeline ----------
// R14 proved gathered gload_lds staging (din fell to ~60us). R14's remaining
// tax: stage -> sync(drain) -> compute exposed full gather latency per step.
// v16 (T3 minimal 2-phase): preload step 0; per step issue stage(ks+1) into
// buf^1 FIRST, compute(ks) from buf, then ONE __syncthreads — the drain
// happens after compute, so the 5 gathers/wave hide under 16 MFMAs+ds_reads.
__global__ __launch_bounds__(256, 3) void din_gemm(
    const int* __restrict__ hist_ids, const int* __restrict__ feedid,
    const u16* __restrict__ HB, const u16* __restrict__ WHP_T,
    const float* __restrict__ qw, const float* __restrict__ b1,
    const float* __restrict__ w2v, float* __restrict__ scores)
{
    __shared__ u16 As[2][64 * 32];    // 8 KB
    __shared__ u16 BsH[2][128 * 32];  // 16 KB
    __shared__ u16 BsP[2][128 * 32];  // 16 KB
    __shared__ float qbs[3 * 128];
    __shared__ float w2s[128];
    __shared__ float sred[64 * 2];

    int t = threadIdx.x, w = t >> 6, lane = t & 63;
    int m0 = blockIdx.x * 64, b0 = m0 / LL;
    int fr = lane & 15, kg8 = (lane >> 4) * 8;
    int wm = (w >> 1) * 32, wn = (w & 1) * 64;

    // ---- prologue: qw+b1, w2 into LDS ----
    for (int idx = t; idx < 384; idx += 256) {
        int bi = idx >> 7, col = idx & 127;
        int bb = b0 + bi; if (bb > BB - 1) bb = BB - 1;
        qbs[idx] = qw[bb * 128 + col] + b1[col];
    }
    if (t < 128) w2s[t] = w2v[t];

    // ---- per-lane staging source pointers (A gathered per-lane) ----
    const u16* a_src = HB + (size_t)hist_ids[m0 + w * 16 + (lane >> 2)] * FDIM
                          + (lane & 3) * 8;
    const u16* b_src0 = WHP_T + (size_t)(w * 32 + (lane >> 2)) * 1024 + (lane & 3) * 8;
    const u16* b_src1 = b_src0 + 16 * 1024;
    const u16* qp0 = HB + (size_t)feedid[(m0 + wm + fr) / LL] * FDIM + kg8;
    const u16* qp1 = HB + (size_t)feedid[(m0 + wm + 16 + fr) / LL] * FDIM + kg8;

    f32x4 acc[2][4];
    f32x4 zz = {0.f, 0.f, 0.f, 0.f};
    #pragma unroll
    for (int i = 0; i < 2; i++)
        #pragma unroll
        for (int j = 0; j < 4; j++) acc[i][j] = zz;

    auto stage = [&](int ks, int buf) {
        int ko = ks * 32;
        load16_lds(a_src + ko,        &As[buf][w * 512]);
        load16_lds(b_src0 + ko,       &BsH[buf][(w * 2) * 512]);
        load16_lds(b_src1 + ko,       &BsH[buf][(w * 2 + 1) * 512]);
        load16_lds(b_src0 + 512 + ko, &BsP[buf][(w * 2) * 512]);
        load16_lds(b_src1 + 512 + ko, &BsP[buf][(w * 2 + 1) * 512]);
    };

    stage(0, 0);
    __syncthreads();                   // drain preload (also covers qbs/w2s)
    #pragma unroll 2
    for (int kt = 0; kt < 16; ++kt) {
        int buf = kt & 1;
        int ko = kt * 32;
        if (kt < 15) stage(kt + 1, buf ^ 1);   // issue next FIRST (in flight)

        // ---- compute step kt from buf ----
        ushort8 qv0 = *(const ushort8*)(qp0 + ko);
        ushort8 qv1 = *(const ushort8*)(qp1 + ko);
        short8 ah0 = *(const short8*)&As[buf][(wm + fr) * 32 + kg8];
        short8 ah1 = *(const short8*)&As[buf][(wm + 16 + fr) * 32 + kg8];
        short8 bh[4], bp[4];
        #pragma unroll
        for (int j = 0; j < 4; ++j) {
            int n = wn + j * 16 + fr;
            bh[j] = *(const short8*)&BsH[buf][n * 32 + kg8];
            bp[j] = *(const short8*)&BsP[buf][n * 32 + kg8];
        }
        #pragma unroll
        for (int j = 0; j < 4; ++j) {
            acc[0][j] = MFMA_BF16(ah0, bh[j], acc[0][j], 0, 0, 0);
            acc[1][j] = MFMA_BF16(ah1, bh[j], acc[1][j], 0, 0, 0);
        }
        ushort8 hv0 = __builtin_bit_cast(ushort8, ah0);
        ushort8 hv1 = __builtin_bit_cast(ushort8, ah1);
        ushort8 pv0, pv1;
        #pragma unroll
        for (int e = 0; e < 8; ++e) {
            pv0[e] = f2bf(bf2f(hv0[e]) * bf2f(qv0[e]));
            pv1[e] = f2bf(bf2f(hv1[e]) * bf2f(qv1[e]));
        }
        short8 ap0 = __builtin_bit_cast(short8, pv0);
        short8 ap1 = __builtin_bit_cast(short8, pv1);
        #pragma unroll
        for (int j = 0; j < 4; ++j) {
            acc[0][j] = MFMA_BF16(ap0, bp[j], acc[0][j], 0, 0, 0);
            acc[1][j] = MFMA_BF16(ap1, bp[j], acc[1][j], 0, 0, 0);
        }
        __syncthreads();               // drain AFTER compute (deferred)
    }

    // ---- epilogue: score[row] = sum_col relu(acc + qw + b1) * w2 ----
    #pragma unroll
    for (int i = 0; i < 2; ++i) {
        #pragma unroll
        for (int r = 0; r < 4; ++r) {
            int rl = wm + i * 16 + (lane >> 4) * 4 + r;
            int bi = (m0 + rl) / LL - b0;
            float s = 0.f;
            #pragma unroll
            for (int j = 0; j < 4; ++j) {
                int col = wn + j * 16 + fr;
                float v = acc[i][j][r] + qbs[bi * 128 + col];
                s += fmaxf(v, 0.f) * w2s[col];
            }
            s += __shfl_xor(s, 1, 64);
            s += __shfl_xor(s, 2, 64);
            s += __shfl_xor(s, 4, 64);
            s += __shfl_xor(s, 8, 64);
            if (fr == 0) sred[rl * 2 + (w & 1)] = s;
        }
    }
    __syncthreads();
    if (t < 64) scores[m0 + t] = sred[t * 2] + sred[t * 2 + 1];
}

// ---------- K4: softmax over L + user_interest (bf16 table, L3-hot) ----------
__global__ __launch_bounds__(256) void softmax_ui(
    const float* __restrict__ scores, const int* __restrict__ hist_ids,
    const u16* __restrict__ HB, u16* __restrict__ dnn_in)
{
    int b = blockIdx.x, t = threadIdx.x;
    int wave = t >> 6, lane = t & 63;
    __shared__ float sc[56];
    __shared__ int hid[56];
    if (t >= 64 && t < 64 + LL) hid[t - 64] = hist_ids[b * LL + (t - 64)];
    if (wave == 0) {
        float x = (lane < LL) ? scores[b * LL + lane] : -1e30f;
        float mx = wave_max(x);
        float e = (lane < LL) ? __expf(x - mx) : 0.f;
        float s = wave_sum(e);
        if (lane < LL) sc[lane] = e / s;
    }
    __syncthreads();
    int d = t * 2;
    float a0 = 0.f, a1 = 0.f;
    #pragma unroll 5
    for (int l = 0; l < LL; ++l) {
        u32 v = *(const u32*)(HB + (size_t)hid[l] * FDIM + d);
        float al = sc[l];
        a0 += al * bf2f((u16)(v & 0xffff));
        a1 += al * bf2f((u16)(v >> 16));
    }
    dnn_in[(size_t)b * KDNN + 648 + d] = f2bf(a0);
    dnn_in[(size_t)b * KDNN + 648 + d + 1] = f2bf(a1);
}

// ---------- K5: MMOE + task heads ----------
__global__ __launch_bounds__(256) void mmoe_head(
    const float* __restrict__ dnn_out, const float* __restrict__ expert_w,
    const float* __restrict__ gate_w, const float* __restrict__ out_w,
    const float* __restrict__ out_b, float* __restrict__ out)
{
    int wave = threadIdx.x >> 6, lane = threadIdx.x & 63;
    int b = blockIdx.x * 4 + wave;
    __shared__ float ds[4][128];
    __shared__ float eo[4][64];
    __shared__ float gt[4][32];
    ds[wave][lane] = dnn_out[b * 128 + lane];
    ds[wave][lane + 64] = dnn_out[b * 128 + 64 + lane];
    __syncthreads();
    int e = lane >> 3, o = lane & 7;
    float acc = 0.f;
    for (int k = 0; k < 128; ++k)
        acc += ds[wave][k] * expert_w[(e * 128 + k) * 8 + o];
    eo[wave][lane] = acc;
    if (lane < 32) {
        int tt = lane >> 3, ee = lane & 7;
        float g = 0.f;
        for (int k = 0; k < 128; ++k)
            g += ds[wave][k] * gate_w[(tt * 128 + k) * 8 + ee];
        float m = g;
        #pragma unroll
        for (int off = 4; off; off >>= 1) m = fmaxf(m, __shfl_xor(m, off, 8));
        float ex = __expf(g - m);
        float s = ex;
        #pragma unroll
        for (int off = 4; off; off >>= 1) s += __shfl_xor(s, off, 8);
        gt[wave][lane] = ex / s;
    }
    __syncthreads();
    if (lane < 32) {
        int tt = lane >> 3, o2 = lane & 7;
        float to = 0.f;
        #pragma unroll
        for (int ee = 0; ee < 8; ++ee)
            to += gt[wave][tt * 8 + ee] * eo[wave][ee * 8 + o2];
        float pl = to * out_w[tt * 8 + o2];
        #pragma unroll
        for (int off = 4; off; off >>= 1) pl += __shfl_xor(pl, off, 8);
        if (o2 == 0) {
            float logit = pl + out_b[tt];
            out[b * 4 + tt] = 1.f / (1.f + __expf(-logit));
        }
    }
}

// ---------- host ----------
extern "C" void kernel_launch(void* const* d_in, const int* in_sizes, int n_in,
                              void* d_out, int out_size, void* d_ws, size_t ws_size,
                              hipStream_t stream)
{
    const int*   sparse_ids = (const int*)d_in[0];
    const float* dense      = (const float*)d_in[1];
    const int*   feedid     = (const int*)d_in[2];
    const int*   hist_ids   = (const int*)d_in[3];
    const float* emb_tables = (const float*)d_in[4];
    const float* feed_table = (const float*)d_in[5];
    const float* attn_w1    = (const float*)d_in[6];
    const float* attn_b1    = (const float*)d_in[7];
    const float* attn_w2    = (const float*)d_in[8];
    const float* attn_b2    = (const float*)d_in[9];
    const float* dnn_w1     = (const float*)d_in[10];
    const float* dnn_b1     = (const float*)d_in[11];
    const float* dnn_w2     = (const float*)d_in[12];
    const float* dnn_b2     = (const float*)d_in[13];
    const float* expert_w   = (const float*)d_in[14];
    const float* gate_w     = (const float*)d_in[15];
    const float* out_w      = (const float*)d_in[16];
    const float* out_b      = (const float*)d_in[17];
    float* out = (float*)d_out;

    char* ws = (char*)d_ws;
    size_t off = 0;
    auto alloc = [&](size_t bytes) {
        char* p = ws + off;
        off += (bytes + 255) & ~(size_t)255;
        return p;
    };
    u16* WHP_T = (u16*)alloc(131072 * 2);
    u16* WQ_T  = (u16*)alloc(65536 * 2);
    u16* W1D_T = (u16*)alloc((size_t)HID1 * KDNN * 2);
    u16* W2D_T = (u16*)alloc((size_t)HID2 * HID1 * 2);
    u16* AQ    = (u16*)alloc((size_t)BB * FDIM * 2);
    float* QW  = (float*)alloc((size_t)BB * 128 * 4);
    u16* DNNIN = (u16*)alloc((size_t)BB * KDNN * 2);
    u16* Z     = (u16*)alloc((size_t)BB * HID1 * 2);
    float* DOUT= (float*)alloc((size_t)BB * HID2 * 4);
    float* SCORES = (float*)alloc((size_t)ROWS * 4);
    unsigned char* FLAGS = (unsigned char*)alloc(100096);
    u16* HB16  = (u16*)alloc((size_t)VF * FDIM * 2);   // 102.4 MB

    zero_flags<<<98, 256, 0, stream>>>((u32*)FLAGS);
    mark_used<<<400, 256, 0, stream>>>(hist_ids, feedid, FLAGS);
    prep_all<<<CVT_BLKS + PREP_BLKS + BB, 256, 0, stream>>>(
        feed_table, HB16, FLAGS, attn_w1, dnn_w1, dnn_w2,
        WHP_T, WQ_T, W1D_T, W2D_T,
        sparse_ids, dense, feedid, emb_tables, DNNIN, AQ);
    gemm_bt<32, false, false><<<dim3(BB / 32, 1), 256, 0, stream>>>(
        AQ, 512, WQ_T, 512, nullptr, QW, BB, 128, 512);
    din_gemm<<<ROWS / 64, 256, 0, stream>>>(
        hist_ids, feedid, HB16, WHP_T, QW, attn_b1, attn_w2, SCORES);
    softmax_ui<<<BB, 256, 0, stream>>>(SCORES, hist_ids, HB16, DNNIN);
    gemm_bt<32, true, true><<<dim3(BB / 32, HID1 / 128), 256, 0, stream>>>(
        DNNIN, KDNN, W1D_T, KDNN, dnn_b1, Z, BB, HID1, KDNN);
    gemm_bt<32, true, false><<<dim3(BB / 32, 1), 256, 0, stream>>>(
        Z, HID1, W2D_T, HID1, dnn_b2, DOUT, BB, HID2, HID1);
    mmoe_head<<<BB / 4, 256, 0, stream>>>(DOUT, expert_w, gate_w, out_w,
                                          out_b, out);
}

// Round 16
// 165.189 us; speedup vs baseline: 1.0001x; 1.0001x over previous
//
#include <hip/hip_runtime.h>
#include <hip/hip_bf16.h>

typedef unsigned short u16;
typedef unsigned int u32;
typedef __attribute__((ext_vector_type(8))) short short8;   // 8 bf16 for MFMA frags
typedef __attribute__((ext_vector_type(8))) u16 ushort8;
typedef __attribute__((ext_vector_type(4))) float f32x4;

// ---------- constants ----------
#define BB 2048
#define SS 8
#define DNUM 8
#define LL 50
#define EDIM 16
#define FDIM 512
#define HID1 256
#define HID2 128
#define VF 100000
#define KDNN 1216          // 1160 padded to 64-multiple
#define ROWS (BB*LL)       // 102400

// ---------- helpers ----------
__device__ inline u16 f2bf(float x) {            // HW RNE cvt (compiler packs)
    return __builtin_bit_cast(u16, __float2bfloat16(x));
}
__device__ inline float bf2f(u16 b) {
    u32 u = ((u32)b) << 16;
    return __builtin_bit_cast(float, u);
}
__device__ inline void load16_lds(const void* g, void* l) {
    __builtin_amdgcn_global_load_lds(
        (const __attribute__((address_space(1))) u32*)g,
        (__attribute__((address_space(3))) u32*)l, 16, 0, 0);
}
__device__ inline float wave_sum(float v) {
    #pragma unroll
    for (int off = 32; off > 0; off >>= 1) v += __shfl_xor(v, off, 64);
    return v;
}
__device__ inline float wave_max(float v) {
    #pragma unroll
    for (int off = 32; off > 0; off >>= 1) v = fmaxf(v, __shfl_xor(v, off, 64));
    return v;
}
__device__ inline void cvt8(const float4& a, const float4& b, ushort8& o) {
    o[0]=f2bf(a.x); o[1]=f2bf(a.y); o[2]=f2bf(a.z); o[3]=f2bf(a.w);
    o[4]=f2bf(b.x); o[5]=f2bf(b.y); o[6]=f2bf(b.z); o[7]=f2bf(b.w);
}

// ---------- K-2: zero used-row flags (re-zeroed every call: determinism) ----------
__global__ __launch_bounds__(256) void zero_flags(u32* __restrict__ f) {
    int i = blockIdx.x * 256 + threadIdx.x;
    if (i < 25024) f[i] = 0;          // 100096 bytes
}

// ---------- K-1: mark rows referenced by hist_ids / feedid ----------
__global__ __launch_bounds__(256) void mark_used(
    const int* __restrict__ hist, const int* __restrict__ feedid,
    unsigned char* __restrict__ flags)
{
    int i = blockIdx.x * 256 + threadIdx.x;
    if (i < ROWS) flags[hist[i]] = 1;
    if (i < BB) flags[feedid[i]] = 1;
}

// ---------- K0 (fused): dedup'd cvt + weight prep + per-b gather ----------
#define CVT_BLKS 25000
#define PREP_BLKS 2112
__global__ __launch_bounds__(256) void prep_all(
    const float* __restrict__ ft, u16* __restrict__ hb,
    const unsigned char* __restrict__ flags,
    const float* __restrict__ w1, const float* __restrict__ dw1,
    const float* __restrict__ dw2,
    u16* __restrict__ WHP_T, u16* __restrict__ WQ_T,
    u16* __restrict__ W1D_T, u16* __restrict__ W2D_T,
    const int* __restrict__ sparse_ids, const float* __restrict__ dense,
    const int* __restrict__ feedid, const float* __restrict__ emb_tables,
    u16* __restrict__ dnn_in, u16* __restrict__ A_q)
{
    int blk = blockIdx.x, t = threadIdx.x;
    if (blk < CVT_BLKS) {
        int r = blk * 4 + (t >> 6);
        if (flags[r]) {
            const float* src = ft + (size_t)r * FDIM + (t & 63) * 8;
            float4 a = *(const float4*)src;
            float4 b = *(const float4*)(src + 4);
            ushort8 o; cvt8(a, b, o);
            *(ushort8*)(hb + (size_t)r * FDIM + (t & 63) * 8) = o;
        }
    } else if (blk < CVT_BLKS + PREP_BLKS) {
        int idx = (blk - CVT_BLKS) * 256 + t;
        if (idx < 131072) {
            int n = idx >> 10, k = idx & 1023;
            float v;
            if (k < 512) v = w1[(512 + k) * 128 + n] - w1[(1024 + k) * 128 + n];
            else         v = w1[(1024 + k) * 128 + n];   // 1536 + (k-512)
            WHP_T[n * 1024 + k] = f2bf(v);
        } else if (idx < 196608) {
            int i = idx - 131072;
            int n = i >> 9, k = i & 511;
            WQ_T[n * 512 + k] = f2bf(w1[k * 128 + n] + w1[(1024 + k) * 128 + n]);
        } else if (idx < 507904) {
            int i = idx - 196608;
            int n = i / KDNN, k = i - n * KDNN;
            W1D_T[i] = (k < 1160) ? f2bf(dw1[k * HID1 + n]) : (u16)0;
        } else if (idx < 540672) {
            int i = idx - 507904;
            int n = i >> 8, k = i & 255;
            W2D_T[i] = f2bf(dw2[k * HID2 + n]);
        }
    } else {
        int b = blk - (CVT_BLKS + PREP_BLKS);
        u16* drow = dnn_in + (size_t)b * KDNN;
        if (t < 128) {
            int s = t >> 4, e = t & 15;
            int id = sparse_ids[b * SS + s];
            float v = emb_tables[(size_t)s * 1600000 + (size_t)id * EDIM + e];
            drow[t] = f2bf(v);
        } else if (t < 136) {
            drow[t] = f2bf(dense[b * DNUM + (t - 128)]);
        } else if (t < 192) {
            drow[1160 + (t - 136)] = 0;   // K padding
        }
        int fid = feedid[b];
        float2 f = *(const float2*)&ft[(size_t)fid * FDIM + t * 2];
        u16 u0 = f2bf(f.x), u1 = f2bf(f.y);
        drow[136 + t * 2] = u0;
        drow[136 + t * 2 + 1] = u1;
        A_q[(size_t)b * FDIM + t * 2] = u0;
        A_q[(size_t)b * FDIM + t * 2 + 1] = u1;
    }
}

// ---------- K2: generic bf16 MFMA GEMM, templated M-tile (R14 form) ----------
template<int BM, bool RELU, bool OUT_BF16>
__global__ __launch_bounds__(256, 4) void gemm_bt(
    const u16* __restrict__ A, int lda,
    const u16* __restrict__ BT, int ldb,
    const float* __restrict__ bias,
    void* __restrict__ Cv, int M, int N, int K)
{
    constexpr int MI = BM / 32;           // frags per wave in M
    __shared__ u16 As[BM * 64];
    __shared__ u16 Bs[128 * 64];
    int m0 = blockIdx.x * BM, n0 = blockIdx.y * 128;
    int tid = threadIdx.x, wave = tid >> 6, lane = tid & 63;
    int lrow = lane >> 3, lk = (lane & 7) * 8;
    f32x4 acc[MI][4];
    f32x4 zz = {0.f, 0.f, 0.f, 0.f};
    #pragma unroll
    for (int i = 0; i < MI; i++)
        #pragma unroll
        for (int j = 0; j < 4; j++) acc[i][j] = zz;
    int wm = (wave >> 1) * (BM / 2), wn = (wave & 1) * 64;

    for (int kt = 0; kt < K; kt += 64) {
        #pragma unroll
        for (int j = 0; j < MI; ++j) {
            int c = wave * MI + j;
            int row = c * 8 + lrow;
            load16_lds(A + (size_t)(m0 + row) * lda + kt + lk, &As[c * 512]);
        }
        #pragma unroll
        for (int j = 0; j < 4; ++j) {
            int c = wave * 4 + j;
            int row = c * 8 + lrow;
            load16_lds(BT + (size_t)(n0 + row) * ldb + kt + lk, &Bs[c * 512]);
        }
        __syncthreads();
        #pragma unroll
        for (int ks = 0; ks < 2; ++ks) {
            int kk = ks * 32 + (lane >> 4) * 8;
            short8 af[MI], bf[4];
            #pragma unroll
            for (int i = 0; i < MI; i++)
                af[i] = *(const short8*)&As[(wm + i * 16 + (lane & 15)) * 64 + kk];
            #pragma unroll
            for (int j = 0; j < 4; j++)
                bf[j] = *(const short8*)&Bs[(wn + j * 16 + (lane & 15)) * 64 + kk];
            #pragma unroll
            for (int i = 0; i < MI; i++)
                #pragma unroll
                for (int j = 0; j < 4; j++)
                    acc[i][j] = __builtin_amdgcn_mfma_f32_16x16x32_bf16(
                        af[i], bf[j], acc[i][j], 0, 0, 0);
        }
        __syncthreads();
    }
    #pragma unroll
    for (int i = 0; i < MI; i++) {
        #pragma unroll
        for (int j = 0; j < 4; j++) {
            #pragma unroll
            for (int r = 0; r < 4; r++) {
                int row = m0 + wm + i * 16 + (lane >> 4) * 4 + r;
                int col = n0 + wn + j * 16 + (lane & 15);
                float v = acc[i][j][r];
                if (bias) v += bias[col];
                if (RELU) v = fmaxf(v, 0.f);
                size_t off = (size_t)row * N + col;
                if (OUT_BF16) ((u16*)Cv)[off] = f2bf(v);
                else ((float*)Cv)[off] = v;
            }
        }
    }
}

#define MFMA_BF16 __builtin_amdgcn_mfma_f32_16x16x32_bf16

// ---------- K3: DIN GEMM v17 — R14 structure at 6 blocks/CU ----------
// Identical to R14's v15 (gathered global_load_lds staging, single-buffered,
// stage -> sync -> compute -> sync) except __launch_bounds__(256,6):
// 23 KB LDS allows 6 blocks/CU (138 KB), and cross-BLOCK staggering is what
// hides the per-step drain (R15 lesson: occupancy > in-block pipelining).
__global__ __launch_bounds__(256, 6) void din_gemm(
    const int* __restrict__ hist_ids, const int* __restrict__ feedid,
    const u16* __restrict__ HB, const u16* __restrict__ WHP_T,
    const float* __restrict__ qw, const float* __restrict__ b1,
    const float* __restrict__ w2v, float* __restrict__ scores)
{
    __shared__ u16 As[64 * 32];       // 4 KB  [row][32k]
    __shared__ u16 BsH[128 * 32];     // 8 KB  [n][32k]
    __shared__ u16 BsP[128 * 32];     // 8 KB
    __shared__ float qbs[3 * 128];
    __shared__ float w2s[128];
    __shared__ float sred[64 * 2];

    int t = threadIdx.x, w = t >> 6, lane = t & 63;
    int m0 = blockIdx.x * 64, b0 = m0 / LL;
    int fr = lane & 15, kg8 = (lane >> 4) * 8;
    int wm = (w >> 1) * 32, wn = (w & 1) * 64;

    // ---- prologue: qw+b1, w2 into LDS ----
    for (int idx = t; idx < 384; idx += 256) {
        int bi = idx >> 7, col = idx & 127;
        int bb = b0 + bi; if (bb > BB - 1) bb = BB - 1;
        qbs[idx] = qw[bb * 128 + col] + b1[col];
    }
    if (t < 128) w2s[t] = w2v[t];

    // ---- per-lane staging source pointers ----
    const u16* a_src = HB + (size_t)hist_ids[m0 + w * 16 + (lane >> 2)] * FDIM
                          + (lane & 3) * 8;
    const u16* b_src0 = WHP_T + (size_t)(w * 32 + (lane >> 2)) * 1024 + (lane & 3) * 8;
    const u16* b_src1 = b_src0 + 16 * 1024;
    const u16* qp0 = HB + (size_t)feedid[(m0 + wm + fr) / LL] * FDIM + kg8;
    const u16* qp1 = HB + (size_t)feedid[(m0 + wm + 16 + fr) / LL] * FDIM + kg8;

    f32x4 acc[2][4];
    f32x4 zz = {0.f, 0.f, 0.f, 0.f};
    #pragma unroll
    for (int i = 0; i < 2; i++)
        #pragma unroll
        for (int j = 0; j < 4; j++) acc[i][j] = zz;

    for (int kt = 0; kt < 16; ++kt) {
        int ko = kt * 32;
        // ---- stage (5 gload/wave, zero register cost, all in flight) ----
        load16_lds(a_src + ko,        &As[w * 512]);
        load16_lds(b_src0 + ko,       &BsH[(w * 2) * 512]);
        load16_lds(b_src1 + ko,       &BsH[(w * 2 + 1) * 512]);
        load16_lds(b_src0 + 512 + ko, &BsP[(w * 2) * 512]);
        load16_lds(b_src1 + 512 + ko, &BsP[(w * 2 + 1) * 512]);
        __syncthreads();               // vmcnt(0) drain — hidden by 6 blocks/CU

        // ---- compute ----
        ushort8 qv0 = *(const ushort8*)(qp0 + ko);
        ushort8 qv1 = *(const ushort8*)(qp1 + ko);
        short8 ah0 = *(const short8*)&As[(wm + fr) * 32 + kg8];
        short8 ah1 = *(const short8*)&As[(wm + 16 + fr) * 32 + kg8];
        short8 bh[4], bp[4];
        #pragma unroll
        for (int j = 0; j < 4; ++j) {
            int n = wn + j * 16 + fr;
            bh[j] = *(const short8*)&BsH[n * 32 + kg8];
            bp[j] = *(const short8*)&BsP[n * 32 + kg8];
        }
        #pragma unroll
        for (int j = 0; j < 4; ++j) {
            acc[0][j] = MFMA_BF16(ah0, bh[j], acc[0][j], 0, 0, 0);
            acc[1][j] = MFMA_BF16(ah1, bh[j], acc[1][j], 0, 0, 0);
        }
        ushort8 hv0 = __builtin_bit_cast(ushort8, ah0);
        ushort8 hv1 = __builtin_bit_cast(ushort8, ah1);
        ushort8 pv0, pv1;
        #pragma unroll
        for (int e = 0; e < 8; ++e) {
            pv0[e] = f2bf(bf2f(hv0[e]) * bf2f(qv0[e]));
            pv1[e] = f2bf(bf2f(hv1[e]) * bf2f(qv1[e]));
        }
        short8 ap0 = __builtin_bit_cast(short8, pv0);
        short8 ap1 = __builtin_bit_cast(short8, pv1);
        #pragma unroll
        for (int j = 0; j < 4; ++j) {
            acc[0][j] = MFMA_BF16(ap0, bp[j], acc[0][j], 0, 0, 0);
            acc[1][j] = MFMA_BF16(ap1, bp[j], acc[1][j], 0, 0, 0);
        }
        __syncthreads();               // before next-step overwrite
    }

    // ---- epilogue: score[row] = sum_col relu(acc + qw + b1) * w2 ----
    #pragma unroll
    for (int i = 0; i < 2; ++i) {
        #pragma unroll
        for (int r = 0; r < 4; ++r) {
            int rl = wm + i * 16 + (lane >> 4) * 4 + r;
            int bi = (m0 + rl) / LL - b0;
            float s = 0.f;
            #pragma unroll
            for (int j = 0; j < 4; ++j) {
                int col = wn + j * 16 + fr;
                float v = acc[i][j][r] + qbs[bi * 128 + col];
                s += fmaxf(v, 0.f) * w2s[col];
            }
            s += __shfl_xor(s, 1, 64);
            s += __shfl_xor(s, 2, 64);
            s += __shfl_xor(s, 4, 64);
            s += __shfl_xor(s, 8, 64);
            if (fr == 0) sred[rl * 2 + (w & 1)] = s;
        }
    }
    __syncthreads();
    if (t < 64) scores[m0 + t] = sred[t * 2] + sred[t * 2 + 1];
}

// ---------- K4: softmax over L + user_interest (bf16 table, L3-hot) ----------
__global__ __launch_bounds__(256) void softmax_ui(
    const float* __restrict__ scores, const int* __restrict__ hist_ids,
    const u16* __restrict__ HB, u16* __restrict__ dnn_in)
{
    int b = blockIdx.x, t = threadIdx.x;
    int wave = t >> 6, lane = t & 63;
    __shared__ float sc[56];
    __shared__ int hid[56];
    if (t >= 64 && t < 64 + LL) hid[t - 64] = hist_ids[b * LL + (t - 64)];
    if (wave == 0) {
        float x = (lane < LL) ? scores[b * LL + lane] : -1e30f;
        float mx = wave_max(x);
        float e = (lane < LL) ? __expf(x - mx) : 0.f;
        float s = wave_sum(e);
        if (lane < LL) sc[lane] = e / s;
    }
    __syncthreads();
    int d = t * 2;
    float a0 = 0.f, a1 = 0.f;
    #pragma unroll 5
    for (int l = 0; l < LL; ++l) {
        u32 v = *(const u32*)(HB + (size_t)hid[l] * FDIM + d);
        float al = sc[l];
        a0 += al * bf2f((u16)(v & 0xffff));
        a1 += al * bf2f((u16)(v >> 16));
    }
    dnn_in[(size_t)b * KDNN + 648 + d] = f2bf(a0);
    dnn_in[(size_t)b * KDNN + 648 + d + 1] = f2bf(a1);
}

// ---------- K5: MMOE + task heads ----------
__global__ __launch_bounds__(256) void mmoe_head(
    const float* __restrict__ dnn_out, const float* __restrict__ expert_w,
    const float* __restrict__ gate_w, const float* __restrict__ out_w,
    const float* __restrict__ out_b, float* __restrict__ out)
{
    int wave = threadIdx.x >> 6, lane = threadIdx.x & 63;
    int b = blockIdx.x * 4 + wave;
    __shared__ float ds[4][128];
    __shared__ float eo[4][64];
    __shared__ float gt[4][32];
    ds[wave][lane] = dnn_out[b * 128 + lane];
    ds[wave][lane + 64] = dnn_out[b * 128 + 64 + lane];
    __syncthreads();
    int e = lane >> 3, o = lane & 7;
    float acc = 0.f;
    for (int k = 0; k < 128; ++k)
        acc += ds[wave][k] * expert_w[(e * 128 + k) * 8 + o];
    eo[wave][lane] = acc;
    if (lane < 32) {
        int tt = lane >> 3, ee = lane & 7;
        float g = 0.f;
        for (int k = 0; k < 128; ++k)
            g += ds[wave][k] * gate_w[(tt * 128 + k) * 8 + ee];
        float m = g;
        #pragma unroll
        for (int off = 4; off; off >>= 1) m = fmaxf(m, __shfl_xor(m, off, 8));
        float ex = __expf(g - m);
        float s = ex;
        #pragma unroll
        for (int off = 4; off; off >>= 1) s += __shfl_xor(s, off, 8);
        gt[wave][lane] = ex / s;
    }
    __syncthreads();
    if (lane < 32) {
        int tt = lane >> 3, o2 = lane & 7;
        float to = 0.f;
        #pragma unroll
        for (int ee = 0; ee < 8; ++ee)
            to += gt[wave][tt * 8 + ee] * eo[wave][ee * 8 + o2];
        float pl = to * out_w[tt * 8 + o2];
        #pragma unroll
        for (int off = 4; off; off >>= 1) pl += __shfl_xor(pl, off, 8);
        if (o2 == 0) {
            float logit = pl + out_b[tt];
            out[b * 4 + tt] = 1.f / (1.f + __expf(-logit));
        }
    }
}

// ---------- host ----------
extern "C" void kernel_launch(void* const* d_in, const int* in_sizes, int n_in,
                              void* d_out, int out_size, void* d_ws, size_t ws_size,
                              hipStream_t stream)
{
    const int*   sparse_ids = (const int*)d_in[0];
    const float* dense      = (const float*)d_in[1];
    const int*   feedid     = (const int*)d_in[2];
    const int*   hist_ids   = (const int*)d_in[3];
    const float* emb_tables = (const float*)d_in[4];
    const float* feed_table = (const float*)d_in[5];
    const float* attn_w1    = (const float*)d_in[6];
    const float* attn_b1    = (const float*)d_in[7];
    const float* attn_w2    = (const float*)d_in[8];
    const float* attn_b2    = (const float*)d_in[9];
    const float* dnn_w1     = (const float*)d_in[10];
    const float* dnn_b1     = (const float*)d_in[11];
    const float* dnn_w2     = (const float*)d_in[12];
    const float* dnn_b2     = (const float*)d_in[13];
    const float* expert_w   = (const float*)d_in[14];
    const float* gate_w     = (const float*)d_in[15];
    const float* out_w      = (const float*)d_in[16];
    const float* out_b      = (const float*)d_in[17];
    float* out = (float*)d_out;

    char* ws = (char*)d_ws;
    size_t off = 0;
    auto alloc = [&](size_t bytes) {
        char* p = ws + off;
        off += (bytes + 255) & ~(size_t)255;
        return p;
    };
    u16* WHP_T = (u16*)alloc(131072 * 2);
    u16* WQ_T  = (u16*)alloc(65536 * 2);
    u16* W1D_T = (u16*)alloc((size_t)HID1 * KDNN * 2);
    u16* W2D_T = (u16*)alloc((size_t)HID2 * HID1 * 2);
    u16* AQ    = (u16*)alloc((size_t)BB * FDIM * 2);
    float* QW  = (float*)alloc((size_t)BB * 128 * 4);
    u16* DNNIN = (u16*)alloc((size_t)BB * KDNN * 2);
    u16* Z     = (u16*)alloc((size_t)BB * HID1 * 2);
    float* DOUT= (float*)alloc((size_t)BB * HID2 * 4);
    float* SCORES = (float*)alloc((size_t)ROWS * 4);
    unsigned char* FLAGS = (unsigned char*)alloc(100096);
    u16* HB16  = (u16*)alloc((size_t)VF * FDIM * 2);   // 102.4 MB

    zero_flags<<<98, 256, 0, stream>>>((u32*)FLAGS);
    mark_used<<<400, 256, 0, stream>>>(hist_ids, feedid, FLAGS);
    prep_all<<<CVT_BLKS + PREP_BLKS + BB, 256, 0, stream>>>(
        feed_table, HB16, FLAGS, attn_w1, dnn_w1, dnn_w2,
        WHP_T, WQ_T, W1D_T, W2D_T,
        sparse_ids, dense, feedid, emb_tables, DNNIN, AQ);
    gemm_bt<32, false, false><<<dim3(BB / 32, 1), 256, 0, stream>>>(
        AQ, 512, WQ_T, 512, nullptr, QW, BB, 128, 512);
    din_gemm<<<ROWS / 64, 256, 0, stream>>>(
        hist_ids, feedid, HB16, WHP_T, QW, attn_b1, attn_w2, SCORES);
    softmax_ui<<<BB, 256, 0, stream>>>(SCORES, hist_ids, HB16, DNNIN);
    gemm_bt<32, true, true><<<dim3(BB / 32, HID1 / 128), 256, 0, stream>>>(
        DNNIN, KDNN, W1D_T, KDNN, dnn_b1, Z, BB, HID1, KDNN);
    gemm_bt<32, true, false><<<dim3(BB / 32, 1), 256, 0, stream>>>(
        Z, HID1, W2D_T, HID1, dnn_b2, DOUT, BB, HID2, HID1);
    mmoe_head<<<BB / 4, 256, 0, stream>>>(DOUT, expert_w, gate_w, out_w,
                                          out_b, out);
}

// Round 17
// 152.646 us; speedup vs baseline: 1.0823x; 1.0822x over previous
//
#include <hip/hip_runtime.h>
#include <hip/hip_bf16.h>

typedef unsigned short u16;
typedef unsigned int u32;
typedef __attribute__((ext_vector_type(8))) short short8;   // 8 bf16 for MFMA frags
typedef __attribute__((ext_vector_type(8))) u16 ushort8;
typedef __attribute__((ext_vector_type(4))) float f32x4;

// ---------- constants ----------
#define BB 2048
#define SS 8
#define DNUM 8
#define LL 50
#define EDIM 16
#define FDIM 512
#define HID1 256
#define HID2 128
#define VF 100000
#define KDNN 1216          // 1160 padded to 64-multiple
#define ROWS (BB*LL)       // 102400

// ---------- helpers ----------
__device__ inline u16 f2bf(float x) {            // HW RNE cvt (compiler packs)
    return __builtin_bit_cast(u16, __float2bfloat16(x));
}
__device__ inline float bf2f(u16 b) {
    u32 u = ((u32)b) << 16;
    return __builtin_bit_cast(float, u);
}
__device__ inline void load16_lds(const void* g, void* l) {
    __builtin_amdgcn_global_load_lds(
        (const __attribute__((address_space(1))) u32*)g,
        (__attribute__((address_space(3))) u32*)l, 16, 0, 0);
}
__device__ inline float wave_sum(float v) {
    #pragma unroll
    for (int off = 32; off > 0; off >>= 1) v += __shfl_xor(v, off, 64);
    return v;
}
__device__ inline float wave_max(float v) {
    #pragma unroll
    for (int off = 32; off > 0; off >>= 1) v = fmaxf(v, __shfl_xor(v, off, 64));
    return v;
}
__device__ inline void cvt8(const float4& a, const float4& b, ushort8& o) {
    o[0]=f2bf(a.x); o[1]=f2bf(a.y); o[2]=f2bf(a.z); o[3]=f2bf(a.w);
    o[4]=f2bf(b.x); o[5]=f2bf(b.y); o[6]=f2bf(b.z); o[7]=f2bf(b.w);
}

// ---------- K-2: zero used-row flags (re-zeroed every call: determinism) ----------
__global__ __launch_bounds__(256) void zero_flags(u32* __restrict__ f) {
    int i = blockIdx.x * 256 + threadIdx.x;
    if (i < 25024) f[i] = 0;          // 100096 bytes
}

// ---------- K-1: mark rows referenced by hist_ids / feedid ----------
__global__ __launch_bounds__(256) void mark_used(
    const int* __restrict__ hist, const int* __restrict__ feedid,
    unsigned char* __restrict__ flags)
{
    int i = blockIdx.x * 256 + threadIdx.x;
    if (i < ROWS) flags[hist[i]] = 1;
    if (i < BB) flags[feedid[i]] = 1;
}

// ---------- K0 (fused): dedup'd cvt + weight prep + per-b gather ----------
#define CVT_BLKS 25000
#define PREP_BLKS 2112
__global__ __launch_bounds__(256) void prep_all(
    const float* __restrict__ ft, u16* __restrict__ hb,
    const unsigned char* __restrict__ flags,
    const float* __restrict__ w1, const float* __restrict__ dw1,
    const float* __restrict__ dw2,
    u16* __restrict__ WHP_T, u16* __restrict__ WQ_T,
    u16* __restrict__ W1D_T, u16* __restrict__ W2D_T,
    const int* __restrict__ sparse_ids, const float* __restrict__ dense,
    const int* __restrict__ feedid, const float* __restrict__ emb_tables,
    u16* __restrict__ dnn_in, u16* __restrict__ A_q)
{
    int blk = blockIdx.x, t = threadIdx.x;
    if (blk < CVT_BLKS) {
        int r = blk * 4 + (t >> 6);
        if (flags[r]) {
            const float* src = ft + (size_t)r * FDIM + (t & 63) * 8;
            float4 a = *(const float4*)src;
            float4 b = *(const float4*)(src + 4);
            ushort8 o; cvt8(a, b, o);
            *(ushort8*)(hb + (size_t)r * FDIM + (t & 63) * 8) = o;
        }
    } else if (blk < CVT_BLKS + PREP_BLKS) {
        int idx = (blk - CVT_BLKS) * 256 + t;
        if (idx < 131072) {
            int n = idx >> 10, k = idx & 1023;
            float v;
            if (k < 512) v = w1[(512 + k) * 128 + n] - w1[(1024 + k) * 128 + n];
            else         v = w1[(1024 + k) * 128 + n];   // 1536 + (k-512)
            WHP_T[n * 1024 + k] = f2bf(v);
        } else if (idx < 196608) {
            int i = idx - 131072;
            int n = i >> 9, k = i & 511;
            WQ_T[n * 512 + k] = f2bf(w1[k * 128 + n] + w1[(1024 + k) * 128 + n]);
        } else if (idx < 507904) {
            int i = idx - 196608;
            int n = i / KDNN, k = i - n * KDNN;
            W1D_T[i] = (k < 1160) ? f2bf(dw1[k * HID1 + n]) : (u16)0;
        } else if (idx < 540672) {
            int i = idx - 507904;
            int n = i >> 8, k = i & 255;
            W2D_T[i] = f2bf(dw2[k * HID2 + n]);
        }
    } else {
        int b = blk - (CVT_BLKS + PREP_BLKS);
        u16* drow = dnn_in + (size_t)b * KDNN;
        if (t < 128) {
            int s = t >> 4, e = t & 15;
            int id = sparse_ids[b * SS + s];
            float v = emb_tables[(size_t)s * 1600000 + (size_t)id * EDIM + e];
            drow[t] = f2bf(v);
        } else if (t < 136) {
            drow[t] = f2bf(dense[b * DNUM + (t - 128)]);
        } else if (t < 192) {
            drow[1160 + (t - 136)] = 0;   // K padding
        }
        int fid = feedid[b];
        float2 f = *(const float2*)&ft[(size_t)fid * FDIM + t * 2];
        u16 u0 = f2bf(f.x), u1 = f2bf(f.y);
        drow[136 + t * 2] = u0;
        drow[136 + t * 2 + 1] = u1;
        A_q[(size_t)b * FDIM + t * 2] = u0;
        A_q[(size_t)b * FDIM + t * 2 + 1] = u1;
    }
}

// ---------- K2: generic bf16 MFMA GEMM, templated M-tile (R14 form) ----------
template<int BM, bool RELU, bool OUT_BF16>
__global__ __launch_bounds__(256, 4) void gemm_bt(
    const u16* __restrict__ A, int lda,
    const u16* __restrict__ BT, int ldb,
    const float* __restrict__ bias,
    void* __restrict__ Cv, int M, int N, int K)
{
    constexpr int MI = BM / 32;           // frags per wave in M
    __shared__ u16 As[BM * 64];
    __shared__ u16 Bs[128 * 64];
    int m0 = blockIdx.x * BM, n0 = blockIdx.y * 128;
    int tid = threadIdx.x, wave = tid >> 6, lane = tid & 63;
    int lrow = lane >> 3, lk = (lane & 7) * 8;
    f32x4 acc[MI][4];
    f32x4 zz = {0.f, 0.f, 0.f, 0.f};
    #pragma unroll
    for (int i = 0; i < MI; i++)
        #pragma unroll
        for (int j = 0; j < 4; j++) acc[i][j] = zz;
    int wm = (wave >> 1) * (BM / 2), wn = (wave & 1) * 64;

    for (int kt = 0; kt < K; kt += 64) {
        #pragma unroll
        for (int j = 0; j < MI; ++j) {
            int c = wave * MI + j;
            int row = c * 8 + lrow;
            load16_lds(A + (size_t)(m0 + row) * lda + kt + lk, &As[c * 512]);
        }
        #pragma unroll
        for (int j = 0; j < 4; ++j) {
            int c = wave * 4 + j;
            int row = c * 8 + lrow;
            load16_lds(BT + (size_t)(n0 + row) * ldb + kt + lk, &Bs[c * 512]);
        }
        __syncthreads();
        #pragma unroll
        for (int ks = 0; ks < 2; ++ks) {
            int kk = ks * 32 + (lane >> 4) * 8;
            short8 af[MI], bf[4];
            #pragma unroll
            for (int i = 0; i < MI; i++)
                af[i] = *(const short8*)&As[(wm + i * 16 + (lane & 15)) * 64 + kk];
            #pragma unroll
            for (int j = 0; j < 4; j++)
                bf[j] = *(const short8*)&Bs[(wn + j * 16 + (lane & 15)) * 64 + kk];
            #pragma unroll
            for (int i = 0; i < MI; i++)
                #pragma unroll
                for (int j = 0; j < 4; j++)
                    acc[i][j] = __builtin_amdgcn_mfma_f32_16x16x32_bf16(
                        af[i], bf[j], acc[i][j], 0, 0, 0);
        }
        __syncthreads();
    }
    #pragma unroll
    for (int i = 0; i < MI; i++) {
        #pragma unroll
        for (int j = 0; j < 4; j++) {
            #pragma unroll
            for (int r = 0; r < 4; r++) {
                int row = m0 + wm + i * 16 + (lane >> 4) * 4 + r;
                int col = n0 + wn + j * 16 + (lane & 15);
                float v = acc[i][j][r];
                if (bias) v += bias[col];
                if (RELU) v = fmaxf(v, 0.f);
                size_t off = (size_t)row * N + col;
                if (OUT_BF16) ((u16*)Cv)[off] = f2bf(v);
                else ((float*)Cv)[off] = v;
            }
        }
    }
}

#define MFMA_BF16 __builtin_amdgcn_mfma_f32_16x16x32_bf16

// ---------- K3: DIN GEMM v18 — counted-vmcnt 2-phase (T4) ----------
// R14 structure + deferred A-gather drain. Compute phase is PURE ds/VALU/MFMA
// (q staged in LDS once) so the compiler inserts no vmem waits. Raw barriers
// with hand-placed s_waitcnt: per iter, compute(kt) -> lgkmcnt(0)+barrier ->
// issue B(kt+1) then A(kt+2) LAST -> vmcnt(1)+barrier (A-gather stays in
// flight a full iteration; B's L2 loads drain per step). A double-buffered.
__global__ __launch_bounds__(256, 4) void din_gemm(
    const int* __restrict__ hist_ids, const int* __restrict__ feedid,
    const u16* __restrict__ HB, const u16* __restrict__ WHP_T,
    const float* __restrict__ qw, const float* __restrict__ b1,
    const float* __restrict__ w2v, float* __restrict__ scores)
{
    __shared__ u16 As[2][64 * 32];    // 8 KB (double-buffered A)
    __shared__ u16 BsH[128 * 32];     // 8 KB
    __shared__ u16 BsP[128 * 32];     // 8 KB
    __shared__ u16 qls[3 * 512];      // 3 KB: q rows (bf16)
    __shared__ float qbs[3 * 128];
    __shared__ float w2s[128];
    __shared__ float sred[64 * 2];

    int t = threadIdx.x, w = t >> 6, lane = t & 63;
    int m0 = blockIdx.x * 64, b0 = m0 / LL;
    int fr = lane & 15, kg8 = (lane >> 4) * 8;
    int wm = (w >> 1) * 32, wn = (w & 1) * 64;

    // ---- prologue: qw+b1, w2 (plain LDS stores) ----
    for (int idx = t; idx < 384; idx += 256) {
        int bi = idx >> 7, col = idx & 127;
        int bb = b0 + bi; if (bb > BB - 1) bb = BB - 1;
        qbs[idx] = qw[bb * 128 + col] + b1[col];
    }
    if (t < 128) w2s[t] = w2v[t];

    // ---- staging source pointers ----
    const u16* a_src = HB + (size_t)hist_ids[m0 + w * 16 + (lane >> 2)] * FDIM
                          + (lane & 3) * 8;
    const u16* b_src0 = WHP_T + (size_t)(w * 32 + (lane >> 2)) * 1024 + (lane & 3) * 8;
    const u16* b_src1 = b_src0 + 16 * 1024;

    // ---- q rows -> LDS (waves 0..2, one row each), issued first ----
    if (w < 3) {
        int bb = b0 + w; if (bb > BB - 1) bb = BB - 1;
        load16_lds(HB + (size_t)feedid[bb] * FDIM + lane * 8, &qls[w * 512]);
    }
    int qb0 = (m0 + wm + fr) / LL - b0;
    int qb1 = (m0 + wm + 16 + fr) / LL - b0;

    f32x4 acc[2][4];
    f32x4 zz = {0.f, 0.f, 0.f, 0.f};
    #pragma unroll
    for (int i = 0; i < 2; i++)
        #pragma unroll
        for (int j = 0; j < 4; j++) acc[i][j] = zz;

    // ---- prologue staging: A(0), B(0), then A(1) LAST (stays in flight) ----
    load16_lds(a_src,         &As[0][w * 512]);
    load16_lds(b_src0,        &BsH[(w * 2) * 512]);
    load16_lds(b_src1,        &BsH[(w * 2 + 1) * 512]);
    load16_lds(b_src0 + 512,  &BsP[(w * 2) * 512]);
    load16_lds(b_src1 + 512,  &BsP[(w * 2 + 1) * 512]);
    load16_lds(a_src + 32,    &As[1][w * 512]);
    asm volatile("s_waitcnt vmcnt(1) lgkmcnt(0)" ::: "memory");
    __builtin_amdgcn_s_barrier();

    #pragma unroll
    for (int kt = 0; kt < 16; ++kt) {
        const int buf = kt & 1;
        const int ko = kt * 32;
        // ---- compute(kt): pure LDS/VALU/MFMA (no vmem => no compiler drains)
        short8 ah0 = *(const short8*)&As[buf][(wm + fr) * 32 + kg8];
        short8 ah1 = *(const short8*)&As[buf][(wm + 16 + fr) * 32 + kg8];
        ushort8 qv0 = *(const ushort8*)&qls[qb0 * 512 + ko + kg8];
        ushort8 qv1 = *(const ushort8*)&qls[qb1 * 512 + ko + kg8];
        short8 bh[4], bp[4];
        #pragma unroll
        for (int j = 0; j < 4; ++j) {
            int n = wn + j * 16 + fr;
            bh[j] = *(const short8*)&BsH[n * 32 + kg8];
            bp[j] = *(const short8*)&BsP[n * 32 + kg8];
        }
        #pragma unroll
        for (int j = 0; j < 4; ++j) {
            acc[0][j] = MFMA_BF16(ah0, bh[j], acc[0][j], 0, 0, 0);
            acc[1][j] = MFMA_BF16(ah1, bh[j], acc[1][j], 0, 0, 0);
        }
        ushort8 hv0 = __builtin_bit_cast(ushort8, ah0);
        ushort8 hv1 = __builtin_bit_cast(ushort8, ah1);
        ushort8 pv0, pv1;
        #pragma unroll
        for (int e = 0; e < 8; ++e) {
            pv0[e] = f2bf(bf2f(hv0[e]) * bf2f(qv0[e]));
            pv1[e] = f2bf(bf2f(hv1[e]) * bf2f(qv1[e]));
        }
        short8 ap0 = __builtin_bit_cast(short8, pv0);
        short8 ap1 = __builtin_bit_cast(short8, pv1);
        #pragma unroll
        for (int j = 0; j < 4; ++j) {
            acc[0][j] = MFMA_BF16(ap0, bp[j], acc[0][j], 0, 0, 0);
            acc[1][j] = MFMA_BF16(ap1, bp[j], acc[1][j], 0, 0, 0);
        }
        // ---- my LDS reads done -> free buffers for overwrite ----
        asm volatile("s_waitcnt lgkmcnt(0)" ::: "memory");
        __builtin_amdgcn_s_barrier();
        // ---- issue next stages: B(kt+1) first, A(kt+2) LAST ----
        if (kt < 15) {
            const int kn = (kt + 1) * 32;
            load16_lds(b_src0 + kn,       &BsH[(w * 2) * 512]);
            load16_lds(b_src1 + kn,       &BsH[(w * 2 + 1) * 512]);
            load16_lds(b_src0 + 512 + kn, &BsP[(w * 2) * 512]);
            load16_lds(b_src1 + 512 + kn, &BsP[(w * 2 + 1) * 512]);
            if (kt < 14) {
                load16_lds(a_src + (kt + 2) * 32, &As[buf][w * 512]);
                asm volatile("s_waitcnt vmcnt(1)" ::: "memory");
            } else {
                asm volatile("s_waitcnt vmcnt(0)" ::: "memory");
            }
            __builtin_amdgcn_s_barrier();
        }
    }

    // ---- epilogue: score[row] = sum_col relu(acc + qw + b1) * w2 ----
    #pragma unroll
    for (int i = 0; i < 2; ++i) {
        #pragma unroll
        for (int r = 0; r < 4; ++r) {
            int rl = wm + i * 16 + (lane >> 4) * 4 + r;
            int bi = (m0 + rl) / LL - b0;
            float s = 0.f;
            #pragma unroll
            for (int j = 0; j < 4; ++j) {
                int col = wn + j * 16 + fr;
                float v = acc[i][j][r] + qbs[bi * 128 + col];
                s += fmaxf(v, 0.f) * w2s[col];
            }
            s += __shfl_xor(s, 1, 64);
            s += __shfl_xor(s, 2, 64);
            s += __shfl_xor(s, 4, 64);
            s += __shfl_xor(s, 8, 64);
            if (fr == 0) sred[rl * 2 + (w & 1)] = s;
        }
    }
    __syncthreads();
    if (t < 64) scores[m0 + t] = sred[t * 2] + sred[t * 2 + 1];
}

// ---------- K4: softmax over L + user_interest (bf16 table, L3-hot) ----------
__global__ __launch_bounds__(256) void softmax_ui(
    const float* __restrict__ scores, const int* __restrict__ hist_ids,
    const u16* __restrict__ HB, u16* __restrict__ dnn_in)
{
    int b = blockIdx.x, t = threadIdx.x;
    int wave = t >> 6, lane = t & 63;
    __shared__ float sc[56];
    __shared__ int hid[56];
    if (t >= 64 && t < 64 + LL) hid[t - 64] = hist_ids[b * LL + (t - 64)];
    if (wave == 0) {
        float x = (lane < LL) ? scores[b * LL + lane] : -1e30f;
        float mx = wave_max(x);
        float e = (lane < LL) ? __expf(x - mx) : 0.f;
        float s = wave_sum(e);
        if (lane < LL) sc[lane] = e / s;
    }
    __syncthreads();
    int d = t * 2;
    float a0 = 0.f, a1 = 0.f;
    #pragma unroll 5
    for (int l = 0; l < LL; ++l) {
        u32 v = *(const u32*)(HB + (size_t)hid[l] * FDIM + d);
        float al = sc[l];
        a0 += al * bf2f((u16)(v & 0xffff));
        a1 += al * bf2f((u16)(v >> 16));
    }
    dnn_in[(size_t)b * KDNN + 648 + d] = f2bf(a0);
    dnn_in[(size_t)b * KDNN + 648 + d + 1] = f2bf(a1);
}

// ---------- K5: MMOE + task heads ----------
__global__ __launch_bounds__(256) void mmoe_head(
    const float* __restrict__ dnn_out, const float* __restrict__ expert_w,
    const float* __restrict__ gate_w, const float* __restrict__ out_w,
    const float* __restrict__ out_b, float* __restrict__ out)
{
    int wave = threadIdx.x >> 6, lane = threadIdx.x & 63;
    int b = blockIdx.x * 4 + wave;
    __shared__ float ds[4][128];
    __shared__ float eo[4][64];
    __shared__ float gt[4][32];
    ds[wave][lane] = dnn_out[b * 128 + lane];
    ds[wave][lane + 64] = dnn_out[b * 128 + 64 + lane];
    __syncthreads();
    int e = lane >> 3, o = lane & 7;
    float acc = 0.f;
    for (int k = 0; k < 128; ++k)
        acc += ds[wave][k] * expert_w[(e * 128 + k) * 8 + o];
    eo[wave][lane] = acc;
    if (lane < 32) {
        int tt = lane >> 3, ee = lane & 7;
        float g = 0.f;
        for (int k = 0; k < 128; ++k)
            g += ds[wave][k] * gate_w[(tt * 128 + k) * 8 + ee];
        float m = g;
        #pragma unroll
        for (int off = 4; off; off >>= 1) m = fmaxf(m, __shfl_xor(m, off, 8));
        float ex = __expf(g - m);
        float s = ex;
        #pragma unroll
        for (int off = 4; off; off >>= 1) s += __shfl_xor(s, off, 8);
        gt[wave][lane] = ex / s;
    }
    __syncthreads();
    if (lane < 32) {
        int tt = lane >> 3, o2 = lane & 7;
        float to = 0.f;
        #pragma unroll
        for (int ee = 0; ee < 8; ++ee)
            to += gt[wave][tt * 8 + ee] * eo[wave][ee * 8 + o2];
        float pl = to * out_w[tt * 8 + o2];
        #pragma unroll
        for (int off = 4; off; off >>= 1) pl += __shfl_xor(pl, off, 8);
        if (o2 == 0) {
            float logit = pl + out_b[tt];
            out[b * 4 + tt] = 1.f / (1.f + __expf(-logit));
        }
    }
}

// ---------- host ----------
extern "C" void kernel_launch(void* const* d_in, const int* in_sizes, int n_in,
                              void* d_out, int out_size, void* d_ws, size_t ws_size,
                              hipStream_t stream)
{
    const int*   sparse_ids = (const int*)d_in[0];
    const float* dense      = (const float*)d_in[1];
    const int*   feedid     = (const int*)d_in[2];
    const int*   hist_ids   = (const int*)d_in[3];
    const float* emb_tables = (const float*)d_in[4];
    const float* feed_table = (const float*)d_in[5];
    const float* attn_w1    = (const float*)d_in[6];
    const float* attn_b1    = (const float*)d_in[7];
    const float* attn_w2    = (const float*)d_in[8];
    const float* attn_b2    = (const float*)d_in[9];
    const float* dnn_w1     = (const float*)d_in[10];
    const float* dnn_b1     = (const float*)d_in[11];
    const float* dnn_w2     = (const float*)d_in[12];
    const float* dnn_b2     = (const float*)d_in[13];
    const float* expert_w   = (const float*)d_in[14];
    const float* gate_w     = (const float*)d_in[15];
    const float* out_w      = (const float*)d_in[16];
    const float* out_b      = (const float*)d_in[17];
    float* out = (float*)d_out;

    char* ws = (char*)d_ws;
    size_t off = 0;
    auto alloc = [&](size_t bytes) {
        char* p = ws + off;
        off += (bytes + 255) & ~(size_t)255;
        return p;
    };
    u16* WHP_T = (u16*)alloc(131072 * 2);
    u16* WQ_T  = (u16*)alloc(65536 * 2);
    u16* W1D_T = (u16*)alloc((size_t)HID1 * KDNN * 2);
    u16* W2D_T = (u16*)alloc((size_t)HID2 * HID1 * 2);
    u16* AQ    = (u16*)alloc((size_t)BB * FDIM * 2);
    float* QW  = (float*)alloc((size_t)BB * 128 * 4);
    u16* DNNIN = (u16*)alloc((size_t)BB * KDNN * 2);
    u16* Z     = (u16*)alloc((size_t)BB * HID1 * 2);
    float* DOUT= (float*)alloc((size_t)BB * HID2 * 4);
    float* SCORES = (float*)alloc((size_t)ROWS * 4);
    unsigned char* FLAGS = (unsigned char*)alloc(100096);
    u16* HB16  = (u16*)alloc((size_t)VF * FDIM * 2);   // 102.4 MB

    zero_flags<<<98, 256, 0, stream>>>((u32*)FLAGS);
    mark_used<<<400, 256, 0, stream>>>(hist_ids, feedid, FLAGS);
    prep_all<<<CVT_BLKS + PREP_BLKS + BB, 256, 0, stream>>>(
        feed_table, HB16, FLAGS, attn_w1, dnn_w1, dnn_w2,
        WHP_T, WQ_T, W1D_T, W2D_T,
        sparse_ids, dense, feedid, emb_tables, DNNIN, AQ);
    gemm_bt<32, false, false><<<dim3(BB / 32, 1), 256, 0, stream>>>(
        AQ, 512, WQ_T, 512, nullptr, QW, BB, 128, 512);
    din_gemm<<<ROWS / 64, 256, 0, stream>>>(
        hist_ids, feedid, HB16, WHP_T, QW, attn_b1, attn_w2, SCORES);
    softmax_ui<<<BB, 256, 0, stream>>>(SCORES, hist_ids, HB16, DNNIN);
    gemm_bt<32, true, true><<<dim3(BB / 32, HID1 / 128), 256, 0, stream>>>(
        DNNIN, KDNN, W1D_T, KDNN, dnn_b1, Z, BB, HID1, KDNN);
    gemm_bt<32, true, false><<<dim3(BB / 32, 1), 256, 0, stream>>>(
        Z, HID1, W2D_T, HID1, dnn_b2, DOUT, BB, HID2, HID1);
    mmoe_head<<<BB / 4, 256, 0, stream>>>(DOUT, expert_w, gate_w, out_w,
                                          out_b, out);
}

// Round 18
// 150.191 us; speedup vs baseline: 1.1000x; 1.0163x over previous
//
#include <hip/hip_runtime.h>
#include <hip/hip_bf16.h>

typedef unsigned short u16;
typedef unsigned int u32;
typedef __attribute__((ext_vector_type(8))) short short8;   // 8 bf16 for MFMA frags
typedef __attribute__((ext_vector_type(8))) u16 ushort8;
typedef __attribute__((ext_vector_type(4))) float f32x4;

// ---------- constants ----------
#define BB 2048
#define SS 8
#define DNUM 8
#define LL 50
#define EDIM 16
#define FDIM 512
#define HID1 256
#define HID2 128
#define VF 100000
#define KDNN 1216          // 1160 padded to 64-multiple
#define ROWS (BB*LL)       // 102400

// ---------- helpers ----------
__device__ inline u16 f2bf(float x) {            // HW RNE cvt (compiler packs)
    return __builtin_bit_cast(u16, __float2bfloat16(x));
}
__device__ inline float bf2f(u16 b) {
    u32 u = ((u32)b) << 16;
    return __builtin_bit_cast(float, u);
}
__device__ inline void load16_lds(const void* g, void* l) {
    __builtin_amdgcn_global_load_lds(
        (const __attribute__((address_space(1))) u32*)g,
        (__attribute__((address_space(3))) u32*)l, 16, 0, 0);
}
__device__ inline float wave_sum(float v) {
    #pragma unroll
    for (int off = 32; off > 0; off >>= 1) v += __shfl_xor(v, off, 64);
    return v;
}
__device__ inline float wave_max(float v) {
    #pragma unroll
    for (int off = 32; off > 0; off >>= 1) v = fmaxf(v, __shfl_xor(v, off, 64));
    return v;
}
__device__ inline void cvt8(const float4& a, const float4& b, ushort8& o) {
    o[0]=f2bf(a.x); o[1]=f2bf(a.y); o[2]=f2bf(a.z); o[3]=f2bf(a.w);
    o[4]=f2bf(b.x); o[5]=f2bf(b.y); o[6]=f2bf(b.z); o[7]=f2bf(b.w);
}

// ---------- K0: weight prep + per-b gather (no table cvt anymore) ----------
#define PREP_BLKS 2112
__global__ __launch_bounds__(256) void prep_small(
    const float* __restrict__ ft,
    const float* __restrict__ w1, const float* __restrict__ dw1,
    const float* __restrict__ dw2,
    u16* __restrict__ WHP_T, u16* __restrict__ WQ_T,
    u16* __restrict__ W1D_T, u16* __restrict__ W2D_T,
    const int* __restrict__ sparse_ids, const float* __restrict__ dense,
    const int* __restrict__ feedid, const float* __restrict__ emb_tables,
    u16* __restrict__ dnn_in, u16* __restrict__ A_q)
{
    int blk = blockIdx.x, t = threadIdx.x;
    if (blk < PREP_BLKS) {
        int idx = blk * 256 + t;
        if (idx < 131072) {
            int n = idx >> 10, k = idx & 1023;
            float v;
            if (k < 512) v = w1[(512 + k) * 128 + n] - w1[(1024 + k) * 128 + n];
            else         v = w1[(1024 + k) * 128 + n];   // 1536 + (k-512)
            WHP_T[n * 1024 + k] = f2bf(v);
        } else if (idx < 196608) {
            int i = idx - 131072;
            int n = i >> 9, k = i & 511;
            WQ_T[n * 512 + k] = f2bf(w1[k * 128 + n] + w1[(1024 + k) * 128 + n]);
        } else if (idx < 507904) {
            int i = idx - 196608;
            int n = i / KDNN, k = i - n * KDNN;
            W1D_T[i] = (k < 1160) ? f2bf(dw1[k * HID1 + n]) : (u16)0;
        } else if (idx < 540672) {
            int i = idx - 507904;
            int n = i >> 8, k = i & 255;
            W2D_T[i] = f2bf(dw2[k * HID2 + n]);
        }
    } else {
        int b = blk - PREP_BLKS;
        u16* drow = dnn_in + (size_t)b * KDNN;
        if (t < 128) {
            int s = t >> 4, e = t & 15;
            int id = sparse_ids[b * SS + s];
            float v = emb_tables[(size_t)s * 1600000 + (size_t)id * EDIM + e];
            drow[t] = f2bf(v);
        } else if (t < 136) {
            drow[t] = f2bf(dense[b * DNUM + (t - 128)]);
        } else if (t < 192) {
            drow[1160 + (t - 136)] = 0;   // K padding
        }
        int fid = feedid[b];
        float2 f = *(const float2*)&ft[(size_t)fid * FDIM + t * 2];
        u16 u0 = f2bf(f.x), u1 = f2bf(f.y);
        drow[136 + t * 2] = u0;
        drow[136 + t * 2 + 1] = u1;
        A_q[(size_t)b * FDIM + t * 2] = u0;
        A_q[(size_t)b * FDIM + t * 2 + 1] = u1;
    }
}

// ---------- K2: generic bf16 MFMA GEMM, templated M-tile (R14/R17 form) ----------
template<int BM, bool RELU, bool OUT_BF16>
__global__ __launch_bounds__(256, 4) void gemm_bt(
    const u16* __restrict__ A, int lda,
    const u16* __restrict__ BT, int ldb,
    const float* __restrict__ bias,
    void* __restrict__ Cv, int M, int N, int K)
{
    constexpr int MI = BM / 32;           // frags per wave in M
    __shared__ u16 As[BM * 64];
    __shared__ u16 Bs[128 * 64];
    int m0 = blockIdx.x * BM, n0 = blockIdx.y * 128;
    int tid = threadIdx.x, wave = tid >> 6, lane = tid & 63;
    int lrow = lane >> 3, lk = (lane & 7) * 8;
    f32x4 acc[MI][4];
    f32x4 zz = {0.f, 0.f, 0.f, 0.f};
    #pragma unroll
    for (int i = 0; i < MI; i++)
        #pragma unroll
        for (int j = 0; j < 4; j++) acc[i][j] = zz;
    int wm = (wave >> 1) * (BM / 2), wn = (wave & 1) * 64;

    for (int kt = 0; kt < K; kt += 64) {
        #pragma unroll
        for (int j = 0; j < MI; ++j) {
            int c = wave * MI + j;
            int row = c * 8 + lrow;
            load16_lds(A + (size_t)(m0 + row) * lda + kt + lk, &As[c * 512]);
        }
        #pragma unroll
        for (int j = 0; j < 4; ++j) {
            int c = wave * 4 + j;
            int row = c * 8 + lrow;
            load16_lds(BT + (size_t)(n0 + row) * ldb + kt + lk, &Bs[c * 512]);
        }
        __syncthreads();
        #pragma unroll
        for (int ks = 0; ks < 2; ++ks) {
            int kk = ks * 32 + (lane >> 4) * 8;
            short8 af[MI], bf[4];
            #pragma unroll
            for (int i = 0; i < MI; i++)
                af[i] = *(const short8*)&As[(wm + i * 16 + (lane & 15)) * 64 + kk];
            #pragma unroll
            for (int j = 0; j < 4; j++)
                bf[j] = *(const short8*)&Bs[(wn + j * 16 + (lane & 15)) * 64 + kk];
            #pragma unroll
            for (int i = 0; i < MI; i++)
                #pragma unroll
                for (int j = 0; j < 4; j++)
                    acc[i][j] = __builtin_amdgcn_mfma_f32_16x16x32_bf16(
                        af[i], bf[j], acc[i][j], 0, 0, 0);
        }
        __syncthreads();
    }
    #pragma unroll
    for (int i = 0; i < MI; i++) {
        #pragma unroll
        for (int j = 0; j < 4; j++) {
            #pragma unroll
            for (int r = 0; r < 4; r++) {
                int row = m0 + wm + i * 16 + (lane >> 4) * 4 + r;
                int col = n0 + wn + j * 16 + (lane & 15);
                float v = acc[i][j][r];
                if (bias) v += bias[col];
                if (RELU) v = fmaxf(v, 0.f);
                size_t off = (size_t)row * N + col;
                if (OUT_BF16) ((u16*)Cv)[off] = f2bf(v);
                else ((float*)Cv)[off] = v;
            }
        }
    }
}

#define MFMA_BF16 __builtin_amdgcn_mfma_f32_16x16x32_bf16

// ---------- K3: DIN GEMM v19 — f32-direct gather, counted-vmcnt 2-phase ----------
// R17 structure, but A gathers come straight from the f32 feed_table (no
// HB16 materialization pass): 2 gloads/wave/step into a k-major-chunk f32
// LDS layout (per-lane source row=lane&15, k4=lane>>4 makes the linear dest
// conflict-free on frag reads — rule #21 source permutation). cvt f32->bf16
// happens in the compute phase (VALU, hidden under MFMAs). q rows cvt'd to
// bf16 in the prologue; compute stays vmem-free so the hand-placed
// vmcnt(2)/lgkmcnt(0) + raw-barrier schedule is preserved verbatim.
__global__ __launch_bounds__(256, 4) void din_gemm(
    const int* __restrict__ hist_ids, const int* __restrict__ feedid,
    const float* __restrict__ ft, const u16* __restrict__ WHP_T,
    const float* __restrict__ qw, const float* __restrict__ b1,
    const float* __restrict__ w2v, float* __restrict__ scores)
{
    __shared__ float Asf[2][64 * 32]; // 16 KB (dbuf f32 A, k-major chunks)
    __shared__ u16 BsH[128 * 32];     // 8 KB
    __shared__ u16 BsP[128 * 32];     // 8 KB
    __shared__ u16 qls[3 * 512];      // 3 KB: q rows (bf16)
    __shared__ float qbs[3 * 128];
    __shared__ float w2s[128];
    __shared__ float sred[64 * 2];

    int t = threadIdx.x, w = t >> 6, lane = t & 63;
    int m0 = blockIdx.x * 64, b0 = m0 / LL;
    int fr = lane & 15, kg8 = (lane >> 4) * 8;
    int wm = (w >> 1) * 32, wn = (w & 1) * 64;

    // ---- prologue: qw+b1, w2, q rows (bf16) — plain LDS stores ----
    for (int idx = t; idx < 384; idx += 256) {
        int bi = idx >> 7, col = idx & 127;
        int bb = b0 + bi; if (bb > BB - 1) bb = BB - 1;
        qbs[idx] = qw[bb * 128 + col] + b1[col];
    }
    if (t < 128) w2s[t] = w2v[t];
    for (int idx = t; idx < 768; idx += 256) {
        int bi = idx >> 8, d2 = (idx & 255) * 2;
        int bb = b0 + bi; if (bb > BB - 1) bb = BB - 1;
        float2 qv = *(const float2*)&ft[(size_t)feedid[bb] * FDIM + d2];
        qls[bi * 512 + d2] = f2bf(qv.x);
        qls[bi * 512 + d2 + 1] = f2bf(qv.y);
    }

    // ---- staging source pointers ----
    // A: per-lane row = lane&15, k4 = lane>>4 (g adds +4) -> linear dest is
    // chunk c = k4*16 + row (16B f32 chunks): frag reads are lane-contiguous.
    const float* a_src0 = ft + (size_t)hist_ids[m0 + w * 16 + fr] * FDIM
                             + (lane >> 4) * 4;
    const float* a_src1 = a_src0 + 16;
    const u16* b_src0 = WHP_T + (size_t)(w * 32 + (lane >> 2)) * 1024 + (lane & 3) * 8;
    const u16* b_src1 = b_src0 + 16 * 1024;

    int qb0 = (m0 + wm + fr) / LL - b0;
    int qb1 = (m0 + wm + 16 + fr) / LL - b0;

    f32x4 acc[2][4];
    f32x4 zz = {0.f, 0.f, 0.f, 0.f};
    #pragma unroll
    for (int i = 0; i < 2; i++)
        #pragma unroll
        for (int j = 0; j < 4; j++) acc[i][j] = zz;

    // ---- prologue staging: A(0), B(0), then A(1) LAST (stays in flight) ----
    load16_lds(a_src0,        &Asf[0][w * 512]);
    load16_lds(a_src1,        &Asf[0][w * 512 + 256]);
    load16_lds(b_src0,        &BsH[(w * 2) * 512]);
    load16_lds(b_src1,        &BsH[(w * 2 + 1) * 512]);
    load16_lds(b_src0 + 512,  &BsP[(w * 2) * 512]);
    load16_lds(b_src1 + 512,  &BsP[(w * 2 + 1) * 512]);
    load16_lds(a_src0 + 32,   &Asf[1][w * 512]);
    load16_lds(a_src1 + 32,   &Asf[1][w * 512 + 256]);
    asm volatile("s_waitcnt vmcnt(2) lgkmcnt(0)" ::: "memory");
    __builtin_amdgcn_s_barrier();

    int ws0 = wm >> 4;                 // A-region indices for frag rows
    int k4a = (lane >> 4) * 2;
    int offA0 = ws0 * 512 + k4a * 64 + fr * 4;
    int offA1 = (ws0 + 1) * 512 + k4a * 64 + fr * 4;

    #pragma unroll
    for (int kt = 0; kt < 16; ++kt) {
        const int buf = kt & 1;
        const int ko = kt * 32;
        // ---- compute(kt): pure LDS/VALU/MFMA ----
        float4 h0a = *(const float4*)&Asf[buf][offA0];
        float4 h0b = *(const float4*)&Asf[buf][offA0 + 64];
        float4 h1a = *(const float4*)&Asf[buf][offA1];
        float4 h1b = *(const float4*)&Asf[buf][offA1 + 64];
        ushort8 hv0, hv1;
        cvt8(h0a, h0b, hv0);
        cvt8(h1a, h1b, hv1);
        ushort8 qv0 = *(const ushort8*)&qls[qb0 * 512 + ko + kg8];
        ushort8 qv1 = *(const ushort8*)&qls[qb1 * 512 + ko + kg8];
        short8 bh[4], bp[4];
        #pragma unroll
        for (int j = 0; j < 4; ++j) {
            int n = wn + j * 16 + fr;
            bh[j] = *(const short8*)&BsH[n * 32 + kg8];
            bp[j] = *(const short8*)&BsP[n * 32 + kg8];
        }
        short8 ah0 = __builtin_bit_cast(short8, hv0);
        short8 ah1 = __builtin_bit_cast(short8, hv1);
        #pragma unroll
        for (int j = 0; j < 4; ++j) {
            acc[0][j] = MFMA_BF16(ah0, bh[j], acc[0][j], 0, 0, 0);
            acc[1][j] = MFMA_BF16(ah1, bh[j], acc[1][j], 0, 0, 0);
        }
        ushort8 pv0, pv1;
        #pragma unroll
        for (int e = 0; e < 8; ++e) {
            pv0[e] = f2bf(bf2f(hv0[e]) * bf2f(qv0[e]));
            pv1[e] = f2bf(bf2f(hv1[e]) * bf2f(qv1[e]));
        }
        short8 ap0 = __builtin_bit_cast(short8, pv0);
        short8 ap1 = __builtin_bit_cast(short8, pv1);
        #pragma unroll
        for (int j = 0; j < 4; ++j) {
            acc[0][j] = MFMA_BF16(ap0, bp[j], acc[0][j], 0, 0, 0);
            acc[1][j] = MFMA_BF16(ap1, bp[j], acc[1][j], 0, 0, 0);
        }
        // ---- my LDS reads done -> free buffers for overwrite ----
        asm volatile("s_waitcnt lgkmcnt(0)" ::: "memory");
        __builtin_amdgcn_s_barrier();
        // ---- issue next stages: B(kt+1) first, A(kt+2) LAST ----
        if (kt < 15) {
            const int knB = (kt + 1) * 32;
            load16_lds(b_src0 + knB,       &BsH[(w * 2) * 512]);
            load16_lds(b_src1 + knB,       &BsH[(w * 2 + 1) * 512]);
            load16_lds(b_src0 + 512 + knB, &BsP[(w * 2) * 512]);
            load16_lds(b_src1 + 512 + knB, &BsP[(w * 2 + 1) * 512]);
            if (kt < 14) {
                const int knA = (kt + 2) * 32;
                load16_lds(a_src0 + knA, &Asf[buf][w * 512]);
                load16_lds(a_src1 + knA, &Asf[buf][w * 512 + 256]);
                asm volatile("s_waitcnt vmcnt(2)" ::: "memory");
            } else {
                asm volatile("s_waitcnt vmcnt(0)" ::: "memory");
            }
            __builtin_amdgcn_s_barrier();
        }
    }

    // ---- epilogue: score[row] = sum_col relu(acc + qw + b1) * w2 ----
    #pragma unroll
    for (int i = 0; i < 2; ++i) {
        #pragma unroll
        for (int r = 0; r < 4; ++r) {
            int rl = wm + i * 16 + (lane >> 4) * 4 + r;
            int bi = (m0 + rl) / LL - b0;
            float s = 0.f;
            #pragma unroll
            for (int j = 0; j < 4; ++j) {
                int col = wn + j * 16 + fr;
                float v = acc[i][j][r] + qbs[bi * 128 + col];
                s += fmaxf(v, 0.f) * w2s[col];
            }
            s += __shfl_xor(s, 1, 64);
            s += __shfl_xor(s, 2, 64);
            s += __shfl_xor(s, 4, 64);
            s += __shfl_xor(s, 8, 64);
            if (fr == 0) sred[rl * 2 + (w & 1)] = s;
        }
    }
    __syncthreads();
    if (t < 64) scores[m0 + t] = sred[t * 2] + sred[t * 2 + 1];
}

// ---------- K4: softmax over L + user_interest (f32 table, L3-hot) ----------
__global__ __launch_bounds__(256) void softmax_ui(
    const float* __restrict__ scores, const int* __restrict__ hist_ids,
    const float* __restrict__ feed_table, u16* __restrict__ dnn_in)
{
    int b = blockIdx.x, t = threadIdx.x;
    int wave = t >> 6, lane = t & 63;
    __shared__ float sc[56];
    __shared__ int hid[56];
    if (t >= 64 && t < 64 + LL) hid[t - 64] = hist_ids[b * LL + (t - 64)];
    if (wave == 0) {
        float x = (lane < LL) ? scores[b * LL + lane] : -1e30f;
        float mx = wave_max(x);
        float e = (lane < LL) ? __expf(x - mx) : 0.f;
        float s = wave_sum(e);
        if (lane < LL) sc[lane] = e / s;
    }
    __syncthreads();
    int d = t * 2;
    float a0 = 0.f, a1 = 0.f;
    #pragma unroll 5
    for (int l = 0; l < LL; ++l) {
        float2 hv = *(const float2*)&feed_table[(size_t)hid[l] * FDIM + d];
        float al = sc[l];
        a0 += al * hv.x;
        a1 += al * hv.y;
    }
    dnn_in[(size_t)b * KDNN + 648 + d] = f2bf(a0);
    dnn_in[(size_t)b * KDNN + 648 + d + 1] = f2bf(a1);
}

// ---------- K5: MMOE + task heads ----------
__global__ __launch_bounds__(256) void mmoe_head(
    const float* __restrict__ dnn_out, const float* __restrict__ expert_w,
    const float* __restrict__ gate_w, const float* __restrict__ out_w,
    const float* __restrict__ out_b, float* __restrict__ out)
{
    int wave = threadIdx.x >> 6, lane = threadIdx.x & 63;
    int b = blockIdx.x * 4 + wave;
    __shared__ float ds[4][128];
    __shared__ float eo[4][64];
    __shared__ float gt[4][32];
    ds[wave][lane] = dnn_out[b * 128 + lane];
    ds[wave][lane + 64] = dnn_out[b * 128 + 64 + lane];
    __syncthreads();
    int e = lane >> 3, o = lane & 7;
    float acc = 0.f;
    for (int k = 0; k < 128; ++k)
        acc += ds[wave][k] * expert_w[(e * 128 + k) * 8 + o];
    eo[wave][lane] = acc;
    if (lane < 32) {
        int tt = lane >> 3, ee = lane & 7;
        float g = 0.f;
        for (int k = 0; k < 128; ++k)
            g += ds[wave][k] * gate_w[(tt * 128 + k) * 8 + ee];
        float m = g;
        #pragma unroll
        for (int off = 4; off; off >>= 1) m = fmaxf(m, __shfl_xor(m, off, 8));
        float ex = __expf(g - m);
        float s = ex;
        #pragma unroll
        for (int off = 4; off; off >>= 1) s += __shfl_xor(s, off, 8);
        gt[wave][lane] = ex / s;
    }
    __syncthreads();
    if (lane < 32) {
        int tt = lane >> 3, o2 = lane & 7;
        float to = 0.f;
        #pragma unroll
        for (int ee = 0; ee < 8; ++ee)
            to += gt[wave][tt * 8 + ee] * eo[wave][ee * 8 + o2];
        float pl = to * out_w[tt * 8 + o2];
        #pragma unroll
        for (int off = 4; off; off >>= 1) pl += __shfl_xor(pl, off, 8);
        if (o2 == 0) {
            float logit = pl + out_b[tt];
            out[b * 4 + tt] = 1.f / (1.f + __expf(-logit));
        }
    }
}

// ---------- host ----------
extern "C" void kernel_launch(void* const* d_in, const int* in_sizes, int n_in,
                              void* d_out, int out_size, void* d_ws, size_t ws_size,
                              hipStream_t stream)
{
    const int*   sparse_ids = (const int*)d_in[0];
    const float* dense      = (const float*)d_in[1];
    const int*   feedid     = (const int*)d_in[2];
    const int*   hist_ids   = (const int*)d_in[3];
    const float* emb_tables = (const float*)d_in[4];
    const float* feed_table = (const float*)d_in[5];
    const float* attn_w1    = (const float*)d_in[6];
    const float* attn_b1    = (const float*)d_in[7];
    const float* attn_w2    = (const float*)d_in[8];
    const float* attn_b2    = (const float*)d_in[9];
    const float* dnn_w1     = (const float*)d_in[10];
    const float* dnn_b1     = (const float*)d_in[11];
    const float* dnn_w2     = (const float*)d_in[12];
    const float* dnn_b2     = (const float*)d_in[13];
    const float* expert_w   = (const float*)d_in[14];
    const float* gate_w     = (const float*)d_in[15];
    const float* out_w      = (const float*)d_in[16];
    const float* out_b      = (const float*)d_in[17];
    float* out = (float*)d_out;
    (void)attn_b2;   // dropped into softmax invariance

    char* ws = (char*)d_ws;
    size_t off = 0;
    auto alloc = [&](size_t bytes) {
        char* p = ws + off;
        off += (bytes + 255) & ~(size_t)255;
        return p;
    };
    u16* WHP_T = (u16*)alloc(131072 * 2);
    u16* WQ_T  = (u16*)alloc(65536 * 2);
    u16* W1D_T = (u16*)alloc((size_t)HID1 * KDNN * 2);
    u16* W2D_T = (u16*)alloc((size_t)HID2 * HID1 * 2);
    u16* AQ    = (u16*)alloc((size_t)BB * FDIM * 2);
    float* QW  = (float*)alloc((size_t)BB * 128 * 4);
    u16* DNNIN = (u16*)alloc((size_t)BB * KDNN * 2);
    u16* Z     = (u16*)alloc((size_t)BB * HID1 * 2);
    float* DOUT= (float*)alloc((size_t)BB * HID2 * 4);
    float* SCORES = (float*)alloc((size_t)ROWS * 4);

    prep_small<<<PREP_BLKS + BB, 256, 0, stream>>>(
        feed_table, attn_w1, dnn_w1, dnn_w2,
        WHP_T, WQ_T, W1D_T, W2D_T,
        sparse_ids, dense, feedid, emb_tables, DNNIN, AQ);
    gemm_bt<32, false, false><<<dim3(BB / 32, 1), 256, 0, stream>>>(
        AQ, 512, WQ_T, 512, nullptr, QW, BB, 128, 512);
    din_gemm<<<ROWS / 64, 256, 0, stream>>>(
        hist_ids, feedid, feed_table, WHP_T, QW, attn_b1, attn_w2, SCORES);
    softmax_ui<<<BB, 256, 0, stream>>>(SCORES, hist_ids, feed_table, DNNIN);
    gemm_bt<32, true, true><<<dim3(BB / 32, HID1 / 128), 256, 0, stream>>>(
        DNNIN, KDNN, W1D_T, KDNN, dnn_b1, Z, BB, HID1, KDNN);
    gemm_bt<32, true, false><<<dim3(BB / 32, 1), 256, 0, stream>>>(
        Z, HID1, W2D_T, HID1, dnn_b2, DOUT, BB, HID2, HID1);
    mmoe_head<<<BB / 4, 256, 0, stream>>>(DOUT, expert_w, gate_w, out_w,
                                          out_b, out);
}

// Round 19
// 138.675 us; speedup vs baseline: 1.1913x; 1.0830x over previous
//
#include <hip/hip_runtime.h>
#include <hip/hip_bf16.h>

typedef unsigned short u16;
typedef unsigned int u32;
typedef __attribute__((ext_vector_type(8))) short short8;   // 8 bf16 for MFMA frags
typedef __attribute__((ext_vector_type(8))) u16 ushort8;
typedef __attribute__((ext_vector_type(4))) float f32x4;

// ---------- constants ----------
#define BB 2048
#define SS 8
#define DNUM 8
#define LL 50
#define EDIM 16
#define FDIM 512
#define HID1 256
#define HID2 128
#define VF 100000
#define KDNN 1216          // 1160 padded to 64-multiple
#define ROWS (BB*LL)       // 102400

// ---------- helpers ----------
__device__ inline u16 f2bf(float x) {            // HW RNE cvt (compiler packs)
    return __builtin_bit_cast(u16, __float2bfloat16(x));
}
__device__ inline float bf2f(u16 b) {
    u32 u = ((u32)b) << 16;
    return __builtin_bit_cast(float, u);
}
__device__ inline void load16_lds(const void* g, void* l) {
    __builtin_amdgcn_global_load_lds(
        (const __attribute__((address_space(1))) u32*)g,
        (__attribute__((address_space(3))) u32*)l, 16, 0, 0);
}
__device__ inline float wave_sum(float v) {
    #pragma unroll
    for (int off = 32; off > 0; off >>= 1) v += __shfl_xor(v, off, 64);
    return v;
}
__device__ inline float wave_max(float v) {
    #pragma unroll
    for (int off = 32; off > 0; off >>= 1) v = fmaxf(v, __shfl_xor(v, off, 64));
    return v;
}
__device__ inline void cvt8(const float4& a, const float4& b, ushort8& o) {
    o[0]=f2bf(a.x); o[1]=f2bf(a.y); o[2]=f2bf(a.z); o[3]=f2bf(a.w);
    o[4]=f2bf(b.x); o[5]=f2bf(b.y); o[6]=f2bf(b.z); o[7]=f2bf(b.w);
}

// ---------- K0: weight prep + per-b gather ----------
#define PREP_BLKS 2112
__global__ __launch_bounds__(256) void prep_small(
    const float* __restrict__ ft,
    const float* __restrict__ w1, const float* __restrict__ dw1,
    const float* __restrict__ dw2,
    u16* __restrict__ WHP_T, u16* __restrict__ WQ_T,
    u16* __restrict__ W1D_T, u16* __restrict__ W2D_T,
    const int* __restrict__ sparse_ids, const float* __restrict__ dense,
    const int* __restrict__ feedid, const float* __restrict__ emb_tables,
    u16* __restrict__ dnn_in, u16* __restrict__ A_q)
{
    int blk = blockIdx.x, t = threadIdx.x;
    if (blk < PREP_BLKS) {
        int idx = blk * 256 + t;
        if (idx < 131072) {
            int n = idx >> 10, k = idx & 1023;
            float v;
            if (k < 512) v = w1[(512 + k) * 128 + n] - w1[(1024 + k) * 128 + n];
            else         v = w1[(1024 + k) * 128 + n];   // 1536 + (k-512)
            WHP_T[n * 1024 + k] = f2bf(v);
        } else if (idx < 196608) {
            int i = idx - 131072;
            int n = i >> 9, k = i & 511;
            WQ_T[n * 512 + k] = f2bf(w1[k * 128 + n] + w1[(1024 + k) * 128 + n]);
        } else if (idx < 507904) {
            int i = idx - 196608;
            int n = i / KDNN, k = i - n * KDNN;
            W1D_T[i] = (k < 1160) ? f2bf(dw1[k * HID1 + n]) : (u16)0;
        } else if (idx < 540672) {
            int i = idx - 507904;
            int n = i >> 8, k = i & 255;
            W2D_T[i] = f2bf(dw2[k * HID2 + n]);
        }
    } else {
        int b = blk - PREP_BLKS;
        u16* drow = dnn_in + (size_t)b * KDNN;
        if (t < 128) {
            int s = t >> 4, e = t & 15;
            int id = sparse_ids[b * SS + s];
            float v = emb_tables[(size_t)s * 1600000 + (size_t)id * EDIM + e];
            drow[t] = f2bf(v);
        } else if (t < 136) {
            drow[t] = f2bf(dense[b * DNUM + (t - 128)]);
        } else if (t < 192) {
            drow[1160 + (t - 136)] = 0;   // K padding
        }
        int fid = feedid[b];
        float2 f = *(const float2*)&ft[(size_t)fid * FDIM + t * 2];
        u16 u0 = f2bf(f.x), u1 = f2bf(f.y);
        drow[136 + t * 2] = u0;
        drow[136 + t * 2 + 1] = u1;
        A_q[(size_t)b * FDIM + t * 2] = u0;
        A_q[(size_t)b * FDIM + t * 2 + 1] = u1;
    }
}

// ---------- K2: generic bf16 MFMA GEMM, templated M-tile ----------
template<int BM, bool RELU, bool OUT_BF16>
__global__ __launch_bounds__(256, 4) void gemm_bt(
    const u16* __restrict__ A, int lda,
    const u16* __restrict__ BT, int ldb,
    const float* __restrict__ bias,
    void* __restrict__ Cv, int M, int N, int K)
{
    constexpr int MI = BM / 32;           // frags per wave in M
    __shared__ u16 As[BM * 64];
    __shared__ u16 Bs[128 * 64];
    int m0 = blockIdx.x * BM, n0 = blockIdx.y * 128;
    int tid = threadIdx.x, wave = tid >> 6, lane = tid & 63;
    int lrow = lane >> 3, lk = (lane & 7) * 8;
    f32x4 acc[MI][4];
    f32x4 zz = {0.f, 0.f, 0.f, 0.f};
    #pragma unroll
    for (int i = 0; i < MI; i++)
        #pragma unroll
        for (int j = 0; j < 4; j++) acc[i][j] = zz;
    int wm = (wave >> 1) * (BM / 2), wn = (wave & 1) * 64;

    for (int kt = 0; kt < K; kt += 64) {
        #pragma unroll
        for (int j = 0; j < MI; ++j) {
            int c = wave * MI + j;
            int row = c * 8 + lrow;
            load16_lds(A + (size_t)(m0 + row) * lda + kt + lk, &As[c * 512]);
        }
        #pragma unroll
        for (int j = 0; j < 4; ++j) {
            int c = wave * 4 + j;
            int row = c * 8 + lrow;
            load16_lds(BT + (size_t)(n0 + row) * ldb + kt + lk, &Bs[c * 512]);
        }
        __syncthreads();
        #pragma unroll
        for (int ks = 0; ks < 2; ++ks) {
            int kk = ks * 32 + (lane >> 4) * 8;
            short8 af[MI], bf[4];
            #pragma unroll
            for (int i = 0; i < MI; i++)
                af[i] = *(const short8*)&As[(wm + i * 16 + (lane & 15)) * 64 + kk];
            #pragma unroll
            for (int j = 0; j < 4; j++)
                bf[j] = *(const short8*)&Bs[(wn + j * 16 + (lane & 15)) * 64 + kk];
            #pragma unroll
            for (int i = 0; i < MI; i++)
                #pragma unroll
                for (int j = 0; j < 4; j++)
                    acc[i][j] = __builtin_amdgcn_mfma_f32_16x16x32_bf16(
                        af[i], bf[j], acc[i][j], 0, 0, 0);
        }
        __syncthreads();
    }
    #pragma unroll
    for (int i = 0; i < MI; i++) {
        #pragma unroll
        for (int j = 0; j < 4; j++) {
            #pragma unroll
            for (int r = 0; r < 4; r++) {
                int row = m0 + wm + i * 16 + (lane >> 4) * 4 + r;
                int col = n0 + wn + j * 16 + (lane & 15);
                float v = acc[i][j][r];
                if (bias) v += bias[col];
                if (RELU) v = fmaxf(v, 0.f);
                size_t off = (size_t)row * N + col;
                if (OUT_BF16) ((u16*)Cv)[off] = f2bf(v);
                else ((float*)Cv)[off] = v;
            }
        }
    }
}

#define MFMA_BF16 __builtin_amdgcn_mfma_f32_16x16x32_bf16

// ---------- K3: DIN fused v20 — one block per sample b ----------
// R18's verified k-loop (f32-direct gather, counted-vmcnt 2-phase), but
// block = one b: 50 real rows + 14 dup(row 49) pad in a 64-row tile. The
// epilogue then owns the full 50-score vector: softmax + user_interest run
// in-block (h rows L1/L2-hot from the gather) -> softmax_ui kernel, SCORES
// buffer, and its 205 MB L3/HBM re-gather are deleted. Single q row.
__global__ __launch_bounds__(256, 4) void din_fused(
    const int* __restrict__ hist_ids, const int* __restrict__ feedid,
    const float* __restrict__ ft, const u16* __restrict__ WHP_T,
    const float* __restrict__ qw, const float* __restrict__ b1,
    const float* __restrict__ w2v, u16* __restrict__ dnn_in)
{
    __shared__ float Asf[2][64 * 32]; // 16 KB (dbuf f32 A, k-major chunks)
    __shared__ u16 BsH[128 * 32];     // 8 KB
    __shared__ u16 BsP[128 * 32];     // 8 KB
    __shared__ u16 qls[512];          // 1 KB: q row (bf16)
    __shared__ float qbs[128];        // qw + b1
    __shared__ float w2s[128];
    __shared__ float sred[64 * 2];
    __shared__ float scf[64];
    __shared__ int hids[64];

    int b = blockIdx.x;
    int t = threadIdx.x, w = t >> 6, lane = t & 63;
    int fr = lane & 15, kg8 = (lane >> 4) * 8;
    int wm = (w >> 1) * 32, wn = (w & 1) * 64;
    int fid = feedid[b];

    // ---- prologue: hids, qw+b1, w2, q row (bf16) — plain LDS stores ----
    if (t < 64) hids[t] = hist_ids[b * LL + (t < LL ? t : LL - 1)];
    if (t < 128) {
        qbs[t] = qw[b * 128 + t] + b1[t];
        w2s[t] = w2v[t];
    }
    {
        float2 qv = *(const float2*)&ft[(size_t)fid * FDIM + t * 2];
        qls[t * 2] = f2bf(qv.x);
        qls[t * 2 + 1] = f2bf(qv.y);
    }

    // ---- staging source pointers (rows >= LL dup row LL-1) ----
    int srow = w * 16 + fr;
    const float* a_src0 = ft + (size_t)hist_ids[b * LL + (srow < LL ? srow : LL - 1)] * FDIM
                             + (lane >> 4) * 4;
    const float* a_src1 = a_src0 + 16;
    const u16* b_src0 = WHP_T + (size_t)(w * 32 + (lane >> 2)) * 1024 + (lane & 3) * 8;
    const u16* b_src1 = b_src0 + 16 * 1024;

    f32x4 acc[2][4];
    f32x4 zz = {0.f, 0.f, 0.f, 0.f};
    #pragma unroll
    for (int i = 0; i < 2; i++)
        #pragma unroll
        for (int j = 0; j < 4; j++) acc[i][j] = zz;

    // ---- prologue staging: A(0), B(0), then A(1) LAST (stays in flight) ----
    load16_lds(a_src0,        &Asf[0][w * 512]);
    load16_lds(a_src1,        &Asf[0][w * 512 + 256]);
    load16_lds(b_src0,        &BsH[(w * 2) * 512]);
    load16_lds(b_src1,        &BsH[(w * 2 + 1) * 512]);
    load16_lds(b_src0 + 512,  &BsP[(w * 2) * 512]);
    load16_lds(b_src1 + 512,  &BsP[(w * 2 + 1) * 512]);
    load16_lds(a_src0 + 32,   &Asf[1][w * 512]);
    load16_lds(a_src1 + 32,   &Asf[1][w * 512 + 256]);
    asm volatile("s_waitcnt vmcnt(2) lgkmcnt(0)" ::: "memory");
    __builtin_amdgcn_s_barrier();

    int ws0 = wm >> 4;
    int k4a = (lane >> 4) * 2;
    int offA0 = ws0 * 512 + k4a * 64 + fr * 4;
    int offA1 = (ws0 + 1) * 512 + k4a * 64 + fr * 4;

    #pragma unroll
    for (int kt = 0; kt < 16; ++kt) {
        const int buf = kt & 1;
        const int ko = kt * 32;
        // ---- compute(kt): pure LDS/VALU/MFMA ----
        float4 h0a = *(const float4*)&Asf[buf][offA0];
        float4 h0b = *(const float4*)&Asf[buf][offA0 + 64];
        float4 h1a = *(const float4*)&Asf[buf][offA1];
        float4 h1b = *(const float4*)&Asf[buf][offA1 + 64];
        ushort8 hv0, hv1;
        cvt8(h0a, h0b, hv0);
        cvt8(h1a, h1b, hv1);
        ushort8 qv = *(const ushort8*)&qls[ko + kg8];
        short8 bh[4], bp[4];
        #pragma unroll
        for (int j = 0; j < 4; ++j) {
            int n = wn + j * 16 + fr;
            bh[j] = *(const short8*)&BsH[n * 32 + kg8];
            bp[j] = *(const short8*)&BsP[n * 32 + kg8];
        }
        short8 ah0 = __builtin_bit_cast(short8, hv0);
        short8 ah1 = __builtin_bit_cast(short8, hv1);
        #pragma unroll
        for (int j = 0; j < 4; ++j) {
            acc[0][j] = MFMA_BF16(ah0, bh[j], acc[0][j], 0, 0, 0);
            acc[1][j] = MFMA_BF16(ah1, bh[j], acc[1][j], 0, 0, 0);
        }
        ushort8 pv0, pv1;
        #pragma unroll
        for (int e = 0; e < 8; ++e) {
            pv0[e] = f2bf(bf2f(hv0[e]) * bf2f(qv[e]));
            pv1[e] = f2bf(bf2f(hv1[e]) * bf2f(qv[e]));
        }
        short8 ap0 = __builtin_bit_cast(short8, pv0);
        short8 ap1 = __builtin_bit_cast(short8, pv1);
        #pragma unroll
        for (int j = 0; j < 4; ++j) {
            acc[0][j] = MFMA_BF16(ap0, bp[j], acc[0][j], 0, 0, 0);
            acc[1][j] = MFMA_BF16(ap1, bp[j], acc[1][j], 0, 0, 0);
        }
        asm volatile("s_waitcnt lgkmcnt(0)" ::: "memory");
        __builtin_amdgcn_s_barrier();
        if (kt < 15) {
            const int knB = (kt + 1) * 32;
            load16_lds(b_src0 + knB,       &BsH[(w * 2) * 512]);
            load16_lds(b_src1 + knB,       &BsH[(w * 2 + 1) * 512]);
            load16_lds(b_src0 + 512 + knB, &BsP[(w * 2) * 512]);
            load16_lds(b_src1 + 512 + knB, &BsP[(w * 2 + 1) * 512]);
            if (kt < 14) {
                const int knA = (kt + 2) * 32;
                load16_lds(a_src0 + knA, &Asf[buf][w * 512]);
                load16_lds(a_src1 + knA, &Asf[buf][w * 512 + 256]);
                asm volatile("s_waitcnt vmcnt(2)" ::: "memory");
            } else {
                asm volatile("s_waitcnt vmcnt(0)" ::: "memory");
            }
            __builtin_amdgcn_s_barrier();
        }
    }

    // ---- epilogue 1: per-row score partials ----
    #pragma unroll
    for (int i = 0; i < 2; ++i) {
        #pragma unroll
        for (int r = 0; r < 4; ++r) {
            int rl = wm + i * 16 + (lane >> 4) * 4 + r;
            float s = 0.f;
            #pragma unroll
            for (int j = 0; j < 4; ++j) {
                int col = wn + j * 16 + fr;
                float v = acc[i][j][r] + qbs[col];
                s += fmaxf(v, 0.f) * w2s[col];
            }
            s += __shfl_xor(s, 1, 64);
            s += __shfl_xor(s, 2, 64);
            s += __shfl_xor(s, 4, 64);
            s += __shfl_xor(s, 8, 64);
            if (fr == 0) sred[rl * 2 + (w & 1)] = s;
        }
    }
    __syncthreads();
    if (t < 64) scf[t] = sred[t * 2] + sred[t * 2 + 1];
    __syncthreads();
    // ---- epilogue 2: softmax over 50 ----
    if (w == 0) {
        float x = (lane < LL) ? scf[lane] : -1e30f;
        float mx = wave_max(x);
        float e = (lane < LL) ? __expf(x - mx) : 0.f;
        float s = wave_sum(e);
        scf[lane] = (lane < LL) ? e / s : 0.f;
    }
    __syncthreads();
    // ---- epilogue 3: user_interest (h rows L1/L2-hot from the gather) ----
    int d = t * 2;
    float a0 = 0.f, a1 = 0.f;
    #pragma unroll 5
    for (int l = 0; l < LL; ++l) {
        float2 hv = *(const float2*)&ft[(size_t)hids[l] * FDIM + d];
        float al = scf[l];
        a0 += al * hv.x;
        a1 += al * hv.y;
    }
    dnn_in[(size_t)b * KDNN + 648 + d] = f2bf(a0);
    dnn_in[(size_t)b * KDNN + 648 + d + 1] = f2bf(a1);
}

// ---------- K5: MMOE + task heads ----------
__global__ __launch_bounds__(256) void mmoe_head(
    const float* __restrict__ dnn_out, const float* __restrict__ expert_w,
    const float* __restrict__ gate_w, const float* __restrict__ out_w,
    const float* __restrict__ out_b, float* __restrict__ out)
{
    int wave = threadIdx.x >> 6, lane = threadIdx.x & 63;
    int b = blockIdx.x * 4 + wave;
    __shared__ float ds[4][128];
    __shared__ float eo[4][64];
    __shared__ float gt[4][32];
    ds[wave][lane] = dnn_out[b * 128 + lane];
    ds[wave][lane + 64] = dnn_out[b * 128 + 64 + lane];
    __syncthreads();
    int e = lane >> 3, o = lane & 7;
    float acc = 0.f;
    for (int k = 0; k < 128; ++k)
        acc += ds[wave][k] * expert_w[(e * 128 + k) * 8 + o];
    eo[wave][lane] = acc;
    if (lane < 32) {
        int tt = lane >> 3, ee = lane & 7;
        float g = 0.f;
        for (int k = 0; k < 128; ++k)
            g += ds[wave][k] * gate_w[(tt * 128 + k) * 8 + ee];
        float m = g;
        #pragma unroll
        for (int off = 4; off; off >>= 1) m = fmaxf(m, __shfl_xor(m, off, 8));
        float ex = __expf(g - m);
        float s = ex;
        #pragma unroll
        for (int off = 4; off; off >>= 1) s += __shfl_xor(s, off, 8);
        gt[wave][lane] = ex / s;
    }
    __syncthreads();
    if (lane < 32) {
        int tt = lane >> 3, o2 = lane & 7;
        float to = 0.f;
        #pragma unroll
        for (int ee = 0; ee < 8; ++ee)
            to += gt[wave][tt * 8 + ee] * eo[wave][ee * 8 + o2];
        float pl = to * out_w[tt * 8 + o2];
        #pragma unroll
        for (int off = 4; off; off >>= 1) pl += __shfl_xor(pl, off, 8);
        if (o2 == 0) {
            float logit = pl + out_b[tt];
            out[b * 4 + tt] = 1.f / (1.f + __expf(-logit));
        }
    }
}

// ---------- host ----------
extern "C" void kernel_launch(void* const* d_in, const int* in_sizes, int n_in,
                              void* d_out, int out_size, void* d_ws, size_t ws_size,
                              hipStream_t stream)
{
    const int*   sparse_ids = (const int*)d_in[0];
    const float* dense      = (const float*)d_in[1];
    const int*   feedid     = (const int*)d_in[2];
    const int*   hist_ids   = (const int*)d_in[3];
    const float* emb_tables = (const float*)d_in[4];
    const float* feed_table = (const float*)d_in[5];
    const float* attn_w1    = (const float*)d_in[6];
    const float* attn_b1    = (const float*)d_in[7];
    const float* attn_w2    = (const float*)d_in[8];
    const float* attn_b2    = (const float*)d_in[9];
    const float* dnn_w1     = (const float*)d_in[10];
    const float* dnn_b1     = (const float*)d_in[11];
    const float* dnn_w2     = (const float*)d_in[12];
    const float* dnn_b2     = (const float*)d_in[13];
    const float* expert_w   = (const float*)d_in[14];
    const float* gate_w     = (const float*)d_in[15];
    const float* out_w      = (const float*)d_in[16];
    const float* out_b      = (const float*)d_in[17];
    float* out = (float*)d_out;
    (void)attn_b2;   // dropped by softmax invariance

    char* ws = (char*)d_ws;
    size_t off = 0;
    auto alloc = [&](size_t bytes) {
        char* p = ws + off;
        off += (bytes + 255) & ~(size_t)255;
        return p;
    };
    u16* WHP_T = (u16*)alloc(131072 * 2);
    u16* WQ_T  = (u16*)alloc(65536 * 2);
    u16* W1D_T = (u16*)alloc((size_t)HID1 * KDNN * 2);
    u16* W2D_T = (u16*)alloc((size_t)HID2 * HID1 * 2);
    u16* AQ    = (u16*)alloc((size_t)BB * FDIM * 2);
    float* QW  = (float*)alloc((size_t)BB * 128 * 4);
    u16* DNNIN = (u16*)alloc((size_t)BB * KDNN * 2);
    u16* Z     = (u16*)alloc((size_t)BB * HID1 * 2);
    float* DOUT= (float*)alloc((size_t)BB * HID2 * 4);

    prep_small<<<PREP_BLKS + BB, 256, 0, stream>>>(
        feed_table, attn_w1, dnn_w1, dnn_w2,
        WHP_T, WQ_T, W1D_T, W2D_T,
        sparse_ids, dense, feedid, emb_tables, DNNIN, AQ);
    gemm_bt<32, false, false><<<dim3(BB / 32, 1), 256, 0, stream>>>(
        AQ, 512, WQ_T, 512, nullptr, QW, BB, 128, 512);
    din_fused<<<BB, 256, 0, stream>>>(
        hist_ids, feedid, feed_table, WHP_T, QW, attn_b1, attn_w2, DNNIN);
    gemm_bt<32, true, true><<<dim3(BB / 32, HID1 / 128), 256, 0, stream>>>(
        DNNIN, KDNN, W1D_T, KDNN, dnn_b1, Z, BB, HID1, KDNN);
    gemm_bt<32, true, false><<<dim3(BB / 32, 1), 256, 0, stream>>>(
        Z, HID1, W2D_T, HID1, dnn_b2, DOUT, BB, HID2, HID1);
    mmoe_head<<<BB / 4, 256, 0, stream>>>(DOUT, expert_w, gate_w, out_w,
                                          out_b, out);
}

// Round 20
// 131.720 us; speedup vs baseline: 1.2542x; 1.0528x over previous
//
#include <hip/hip_runtime.h>
#include <hip/hip_bf16.h>

typedef unsigned short u16;
typedef unsigned int u32;
typedef __attribute__((ext_vector_type(8))) short short8;   // 8 bf16 for MFMA frags
typedef __attribute__((ext_vector_type(8))) u16 ushort8;
typedef __attribute__((ext_vector_type(4))) float f32x4;

// ---------- constants ----------
#define BB 2048
#define SS 8
#define DNUM 8
#define LL 50
#define EDIM 16
#define FDIM 512
#define HID1 256
#define HID2 128
#define VF 100000
#define KDNN 1216          // 1160 padded to 64-multiple
#define ROWS (BB*LL)       // 102400

// ---------- helpers ----------
__device__ inline u16 f2bf(float x) {            // HW RNE cvt (compiler packs)
    return __builtin_bit_cast(u16, __float2bfloat16(x));
}
__device__ inline float bf2f(u16 b) {
    u32 u = ((u32)b) << 16;
    return __builtin_bit_cast(float, u);
}
__device__ inline void load16_lds(const void* g, void* l) {
    __builtin_amdgcn_global_load_lds(
        (const __attribute__((address_space(1))) u32*)g,
        (__attribute__((address_space(3))) u32*)l, 16, 0, 0);
}
__device__ inline float wave_sum(float v) {
    #pragma unroll
    for (int off = 32; off > 0; off >>= 1) v += __shfl_xor(v, off, 64);
    return v;
}
__device__ inline float wave_max(float v) {
    #pragma unroll
    for (int off = 32; off > 0; off >>= 1) v = fmaxf(v, __shfl_xor(v, off, 64));
    return v;
}
__device__ inline void cvt8(const float4& a, const float4& b, ushort8& o) {
    o[0]=f2bf(a.x); o[1]=f2bf(a.y); o[2]=f2bf(a.z); o[3]=f2bf(a.w);
    o[4]=f2bf(b.x); o[5]=f2bf(b.y); o[6]=f2bf(b.z); o[7]=f2bf(b.w);
}

// ---------- K0: weight prep + per-b gather ----------
// WHP_S [128n][1024k] PRE-SWIZZLED within each 32-k tile:
//   ks = (k&~31) | ((k&31) ^ ((n&3)<<3))
// so din's swizzled ds_read spreads the 64B n-stride bank collisions
// (8-way -> residual 4-way). Staging copies the tile linearly (rule #21).
#define PREP_BLKS 2112
__global__ __launch_bounds__(256) void prep_small(
    const float* __restrict__ ft,
    const float* __restrict__ w1, const float* __restrict__ dw1,
    const float* __restrict__ dw2,
    u16* __restrict__ WHP_S, u16* __restrict__ WQ_T,
    u16* __restrict__ W1D_T, u16* __restrict__ W2D_T,
    const int* __restrict__ sparse_ids, const float* __restrict__ dense,
    const int* __restrict__ feedid, const float* __restrict__ emb_tables,
    u16* __restrict__ dnn_in, u16* __restrict__ A_q)
{
    int blk = blockIdx.x, t = threadIdx.x;
    if (blk < PREP_BLKS) {
        int idx = blk * 256 + t;
        if (idx < 131072) {
            int n = idx >> 10, k = idx & 1023;
            float v;
            if (k < 512) v = w1[(512 + k) * 128 + n] - w1[(1024 + k) * 128 + n];
            else         v = w1[(1024 + k) * 128 + n];   // 1536 + (k-512)
            int ks = (k & ~31) | ((k & 31) ^ ((n & 3) << 3));
            WHP_S[n * 1024 + ks] = f2bf(v);
        } else if (idx < 196608) {
            int i = idx - 131072;
            int n = i >> 9, k = i & 511;
            WQ_T[n * 512 + k] = f2bf(w1[k * 128 + n] + w1[(1024 + k) * 128 + n]);
        } else if (idx < 507904) {
            int i = idx - 196608;
            int n = i / KDNN, k = i - n * KDNN;
            W1D_T[i] = (k < 1160) ? f2bf(dw1[k * HID1 + n]) : (u16)0;
        } else if (idx < 540672) {
            int i = idx - 507904;
            int n = i >> 8, k = i & 255;
            W2D_T[i] = f2bf(dw2[k * HID2 + n]);
        }
    } else {
        int b = blk - PREP_BLKS;
        u16* drow = dnn_in + (size_t)b * KDNN;
        if (t < 128) {
            int s = t >> 4, e = t & 15;
            int id = sparse_ids[b * SS + s];
            float v = emb_tables[(size_t)s * 1600000 + (size_t)id * EDIM + e];
            drow[t] = f2bf(v);
        } else if (t < 136) {
            drow[t] = f2bf(dense[b * DNUM + (t - 128)]);
        } else if (t < 192) {
            drow[1160 + (t - 136)] = 0;   // K padding
        }
        int fid = feedid[b];
        float2 f = *(const float2*)&ft[(size_t)fid * FDIM + t * 2];
        u16 u0 = f2bf(f.x), u1 = f2bf(f.y);
        drow[136 + t * 2] = u0;
        drow[136 + t * 2 + 1] = u1;
        A_q[(size_t)b * FDIM + t * 2] = u0;
        A_q[(size_t)b * FDIM + t * 2 + 1] = u1;
    }
}

// ---------- K2: generic bf16 MFMA GEMM, templated M/N tiles ----------
template<int BM, int BN, bool RELU, bool OUT_BF16>
__global__ __launch_bounds__(256, 4) void gemm_bt(
    const u16* __restrict__ A, int lda,
    const u16* __restrict__ BT, int ldb,
    const float* __restrict__ bias,
    void* __restrict__ Cv, int M, int N, int K)
{
    constexpr int MI = BM / 32;           // m-frags per wave
    constexpr int NJ = BN / 32;           // n-frags per wave
    __shared__ u16 As[BM * 64];
    __shared__ u16 Bs[BN * 64];
    int m0 = blockIdx.x * BM, n0 = blockIdx.y * BN;
    int tid = threadIdx.x, wave = tid >> 6, lane = tid & 63;
    int lrow = lane >> 3, lk = (lane & 7) * 8;
    f32x4 acc[MI][NJ];
    f32x4 zz = {0.f, 0.f, 0.f, 0.f};
    #pragma unroll
    for (int i = 0; i < MI; i++)
        #pragma unroll
        for (int j = 0; j < NJ; j++) acc[i][j] = zz;
    int wm = (wave >> 1) * (BM / 2), wn = (wave & 1) * (BN / 2);

    for (int kt = 0; kt < K; kt += 64) {
        #pragma unroll
        for (int j = 0; j < MI; ++j) {
            int c = wave * MI + j;
            int row = c * 8 + lrow;
            load16_lds(A + (size_t)(m0 + row) * lda + kt + lk, &As[c * 512]);
        }
        #pragma unroll
        for (int j = 0; j < NJ; ++j) {
            int c = wave * NJ + j;
            int row = c * 8 + lrow;
            load16_lds(BT + (size_t)(n0 + row) * ldb + kt + lk, &Bs[c * 512]);
        }
        __syncthreads();
        #pragma unroll
        for (int ks = 0; ks < 2; ++ks) {
            int kk = ks * 32 + (lane >> 4) * 8;
            short8 af[MI], bf[NJ];
            #pragma unroll
            for (int i = 0; i < MI; i++)
                af[i] = *(const short8*)&As[(wm + i * 16 + (lane & 15)) * 64 + kk];
            #pragma unroll
            for (int j = 0; j < NJ; j++)
                bf[j] = *(const short8*)&Bs[(wn + j * 16 + (lane & 15)) * 64 + kk];
            #pragma unroll
            for (int i = 0; i < MI; i++)
                #pragma unroll
                for (int j = 0; j < NJ; j++)
                    acc[i][j] = __builtin_amdgcn_mfma_f32_16x16x32_bf16(
                        af[i], bf[j], acc[i][j], 0, 0, 0);
        }
        __syncthreads();
    }
    #pragma unroll
    for (int i = 0; i < MI; i++) {
        #pragma unroll
        for (int j = 0; j < NJ; j++) {
            #pragma unroll
            for (int r = 0; r < 4; r++) {
                int row = m0 + wm + i * 16 + (lane >> 4) * 4 + r;
                int col = n0 + wn + j * 16 + (lane & 15);
                float v = acc[i][j][r];
                if (bias) v += bias[col];
                if (RELU) v = fmaxf(v, 0.f);
                size_t off = (size_t)row * N + col;
                if (OUT_BF16) ((u16*)Cv)[off] = f2bf(v);
                else ((float*)Cv)[off] = v;
            }
        }
    }
}

#define MFMA_BF16 __builtin_amdgcn_mfma_f32_16x16x32_bf16

// ---------- K3: DIN fused v21 — one block per b, swizzled B ----------
// R19 structure (f32-direct gather, counted-vmcnt 2-phase, fused
// softmax+UI), plus the R6-verified swizzle pair: WHP_S pre-swizzled in
// 32-k tiles, linear gload_lds staging, swizzled ds_read
// (kk = kg8 ^ ((n&3)<<3)) — B-frag bank conflicts 8-way -> 4-way.
__global__ __launch_bounds__(256, 4) void din_fused(
    const int* __restrict__ hist_ids, const int* __restrict__ feedid,
    const float* __restrict__ ft, const u16* __restrict__ WHP_S,
    const float* __restrict__ qw, const float* __restrict__ b1,
    const float* __restrict__ w2v, u16* __restrict__ dnn_in)
{
    __shared__ float Asf[2][64 * 32]; // 16 KB (dbuf f32 A, k-major chunks)
    __shared__ u16 BsH[128 * 32];     // 8 KB (swizzled content)
    __shared__ u16 BsP[128 * 32];     // 8 KB
    __shared__ u16 qls[512];          // 1 KB: q row (bf16)
    __shared__ float qbs[128];        // qw + b1
    __shared__ float w2s[128];
    __shared__ float sred[64 * 2];
    __shared__ float scf[64];
    __shared__ int hids[64];

    int b = blockIdx.x;
    int t = threadIdx.x, w = t >> 6, lane = t & 63;
    int fr = lane & 15, kg8 = (lane >> 4) * 8;
    int wm = (w >> 1) * 32, wn = (w & 1) * 64;
    int fid = feedid[b];

    // ---- prologue: hids, qw+b1, w2, q row (bf16) — plain LDS stores ----
    if (t < 64) hids[t] = hist_ids[b * LL + (t < LL ? t : LL - 1)];
    if (t < 128) {
        qbs[t] = qw[b * 128 + t] + b1[t];
        w2s[t] = w2v[t];
    }
    {
        float2 qv = *(const float2*)&ft[(size_t)fid * FDIM + t * 2];
        qls[t * 2] = f2bf(qv.x);
        qls[t * 2 + 1] = f2bf(qv.y);
    }

    // ---- staging source pointers (rows >= LL dup row LL-1) ----
    int srow = w * 16 + fr;
    const float* a_src0 = ft + (size_t)hist_ids[b * LL + (srow < LL ? srow : LL - 1)] * FDIM
                             + (lane >> 4) * 4;
    const float* a_src1 = a_src0 + 16;
    const u16* b_src0 = WHP_S + (size_t)(w * 32 + (lane >> 2)) * 1024 + (lane & 3) * 8;
    const u16* b_src1 = b_src0 + 16 * 1024;

    f32x4 acc[2][4];
    f32x4 zz = {0.f, 0.f, 0.f, 0.f};
    #pragma unroll
    for (int i = 0; i < 2; i++)
        #pragma unroll
        for (int j = 0; j < 4; j++) acc[i][j] = zz;

    // ---- prologue staging: A(0), B(0), then A(1) LAST (stays in flight) ----
    load16_lds(a_src0,        &Asf[0][w * 512]);
    load16_lds(a_src1,        &Asf[0][w * 512 + 256]);
    load16_lds(b_src0,        &BsH[(w * 2) * 512]);
    load16_lds(b_src1,        &BsH[(w * 2 + 1) * 512]);
    load16_lds(b_src0 + 512,  &BsP[(w * 2) * 512]);
    load16_lds(b_src1 + 512,  &BsP[(w * 2 + 1) * 512]);
    load16_lds(a_src0 + 32,   &Asf[1][w * 512]);
    load16_lds(a_src1 + 32,   &Asf[1][w * 512 + 256]);
    asm volatile("s_waitcnt vmcnt(2) lgkmcnt(0)" ::: "memory");
    __builtin_amdgcn_s_barrier();

    int ws0 = wm >> 4;
    int k4a = (lane >> 4) * 2;
    int offA0 = ws0 * 512 + k4a * 64 + fr * 4;
    int offA1 = (ws0 + 1) * 512 + k4a * 64 + fr * 4;

    #pragma unroll
    for (int kt = 0; kt < 16; ++kt) {
        const int buf = kt & 1;
        const int ko = kt * 32;
        // ---- compute(kt): pure LDS/VALU/MFMA ----
        float4 h0a = *(const float4*)&Asf[buf][offA0];
        float4 h0b = *(const float4*)&Asf[buf][offA0 + 64];
        float4 h1a = *(const float4*)&Asf[buf][offA1];
        float4 h1b = *(const float4*)&Asf[buf][offA1 + 64];
        ushort8 hv0, hv1;
        cvt8(h0a, h0b, hv0);
        cvt8(h1a, h1b, hv1);
        ushort8 qv = *(const ushort8*)&qls[ko + kg8];
        short8 bh[4], bp[4];
        #pragma unroll
        for (int j = 0; j < 4; ++j) {
            int n = wn + j * 16 + fr;
            int kk = kg8 ^ ((n & 3) << 3);        // swizzled read
            bh[j] = *(const short8*)&BsH[n * 32 + kk];
            bp[j] = *(const short8*)&BsP[n * 32 + kk];
        }
        short8 ah0 = __builtin_bit_cast(short8, hv0);
        short8 ah1 = __builtin_bit_cast(short8, hv1);
        #pragma unroll
        for (int j = 0; j < 4; ++j) {
            acc[0][j] = MFMA_BF16(ah0, bh[j], acc[0][j], 0, 0, 0);
            acc[1][j] = MFMA_BF16(ah1, bh[j], acc[1][j], 0, 0, 0);
        }
        ushort8 pv0, pv1;
        #pragma unroll
        for (int e = 0; e < 8; ++e) {
            pv0[e] = f2bf(bf2f(hv0[e]) * bf2f(qv[e]));
            pv1[e] = f2bf(bf2f(hv1[e]) * bf2f(qv[e]));
        }
        short8 ap0 = __builtin_bit_cast(short8, pv0);
        short8 ap1 = __builtin_bit_cast(short8, pv1);
        #pragma unroll
        for (int j = 0; j < 4; ++j) {
            acc[0][j] = MFMA_BF16(ap0, bp[j], acc[0][j], 0, 0, 0);
            acc[1][j] = MFMA_BF16(ap1, bp[j], acc[1][j], 0, 0, 0);
        }
        asm volatile("s_waitcnt lgkmcnt(0)" ::: "memory");
        __builtin_amdgcn_s_barrier();
        if (kt < 15) {
            const int knB = (kt + 1) * 32;
            load16_lds(b_src0 + knB,       &BsH[(w * 2) * 512]);
            load16_lds(b_src1 + knB,       &BsH[(w * 2 + 1) * 512]);
            load16_lds(b_src0 + 512 + knB, &BsP[(w * 2) * 512]);
            load16_lds(b_src1 + 512 + knB, &BsP[(w * 2 + 1) * 512]);
            if (kt < 14) {
                const int knA = (kt + 2) * 32;
                load16_lds(a_src0 + knA, &Asf[buf][w * 512]);
                load16_lds(a_src1 + knA, &Asf[buf][w * 512 + 256]);
                asm volatile("s_waitcnt vmcnt(2)" ::: "memory");
            } else {
                asm volatile("s_waitcnt vmcnt(0)" ::: "memory");
            }
            __builtin_amdgcn_s_barrier();
        }
    }

    // ---- epilogue 1: per-row score partials ----
    #pragma unroll
    for (int i = 0; i < 2; ++i) {
        #pragma unroll
        for (int r = 0; r < 4; ++r) {
            int rl = wm + i * 16 + (lane >> 4) * 4 + r;
            float s = 0.f;
            #pragma unroll
            for (int j = 0; j < 4; ++j) {
                int col = wn + j * 16 + fr;
                float v = acc[i][j][r] + qbs[col];
                s += fmaxf(v, 0.f) * w2s[col];
            }
            s += __shfl_xor(s, 1, 64);
            s += __shfl_xor(s, 2, 64);
            s += __shfl_xor(s, 4, 64);
            s += __shfl_xor(s, 8, 64);
            if (fr == 0) sred[rl * 2 + (w & 1)] = s;
        }
    }
    __syncthreads();
    if (t < 64) scf[t] = sred[t * 2] + sred[t * 2 + 1];
    __syncthreads();
    // ---- epilogue 2: softmax over 50 ----
    if (w == 0) {
        float x = (lane < LL) ? scf[lane] : -1e30f;
        float mx = wave_max(x);
        float e = (lane < LL) ? __expf(x - mx) : 0.f;
        float s = wave_sum(e);
        scf[lane] = (lane < LL) ? e / s : 0.f;
    }
    __syncthreads();
    // ---- epilogue 3: user_interest (h rows L1/L2-hot from the gather) ----
    int d = t * 2;
    float a0 = 0.f, a1 = 0.f;
    #pragma unroll 5
    for (int l = 0; l < LL; ++l) {
        float2 hv = *(const float2*)&ft[(size_t)hids[l] * FDIM + d];
        float al = scf[l];
        a0 += al * hv.x;
        a1 += al * hv.y;
    }
    dnn_in[(size_t)b * KDNN + 648 + d] = f2bf(a0);
    dnn_in[(size_t)b * KDNN + 648 + d + 1] = f2bf(a1);
}

// ---------- K5: MMOE + task heads ----------
__global__ __launch_bounds__(256) void mmoe_head(
    const float* __restrict__ dnn_out, const float* __restrict__ expert_w,
    const float* __restrict__ gate_w, const float* __restrict__ out_w,
    const float* __restrict__ out_b, float* __restrict__ out)
{
    int wave = threadIdx.x >> 6, lane = threadIdx.x & 63;
    int b = blockIdx.x * 4 + wave;
    __shared__ float ds[4][128];
    __shared__ float eo[4][64];
    __shared__ float gt[4][32];
    ds[wave][lane] = dnn_out[b * 128 + lane];
    ds[wave][lane + 64] = dnn_out[b * 128 + 64 + lane];
    __syncthreads();
    int e = lane >> 3, o = lane & 7;
    float acc = 0.f;
    for (int k = 0; k < 128; ++k)
        acc += ds[wave][k] * expert_w[(e * 128 + k) * 8 + o];
    eo[wave][lane] = acc;
    if (lane < 32) {
        int tt = lane >> 3, ee = lane & 7;
        float g = 0.f;
        for (int k = 0; k < 128; ++k)
            g += ds[wave][k] * gate_w[(tt * 128 + k) * 8 + ee];
        float m = g;
        #pragma unroll
        for (int off = 4; off; off >>= 1) m = fmaxf(m, __shfl_xor(m, off, 8));
        float ex = __expf(g - m);
        float s = ex;
        #pragma unroll
        for (int off = 4; off; off >>= 1) s += __shfl_xor(s, off, 8);
        gt[wave][lane] = ex / s;
    }
    __syncthreads();
    if (lane < 32) {
        int tt = lane >> 3, o2 = lane & 7;
        float to = 0.f;
        #pragma unroll
        for (int ee = 0; ee < 8; ++ee)
            to += gt[wave][tt * 8 + ee] * eo[wave][ee * 8 + o2];
        float pl = to * out_w[tt * 8 + o2];
        #pragma unroll
        for (int off = 4; off; off >>= 1) pl += __shfl_xor(pl, off, 8);
        if (o2 == 0) {
            float logit = pl + out_b[tt];
            out[b * 4 + tt] = 1.f / (1.f + __expf(-logit));
        }
    }
}

// ---------- host ----------
extern "C" void kernel_launch(void* const* d_in, const int* in_sizes, int n_in,
                              void* d_out, int out_size, void* d_ws, size_t ws_size,
                              hipStream_t stream)
{
    const int*   sparse_ids = (const int*)d_in[0];
    const float* dense      = (const float*)d_in[1];
    const int*   feedid     = (const int*)d_in[2];
    const int*   hist_ids   = (const int*)d_in[3];
    const float* emb_tables = (const float*)d_in[4];
    const float* feed_table = (const float*)d_in[5];
    const float* attn_w1    = (const float*)d_in[6];
    const float* attn_b1    = (const float*)d_in[7];
    const float* attn_w2    = (const float*)d_in[8];
    const float* attn_b2    = (const float*)d_in[9];
    const float* dnn_w1     = (const float*)d_in[10];
    const float* dnn_b1     = (const float*)d_in[11];
    const float* dnn_w2     = (const float*)d_in[12];
    const float* dnn_b2     = (const float*)d_in[13];
    const float* expert_w   = (const float*)d_in[14];
    const float* gate_w     = (const float*)d_in[15];
    const float* out_w      = (const float*)d_in[16];
    const float* out_b      = (const float*)d_in[17];
    float* out = (float*)d_out;
    (void)attn_b2;   // dropped by softmax invariance

    char* ws = (char*)d_ws;
    size_t off = 0;
    auto alloc = [&](size_t bytes) {
        char* p = ws + off;
        off += (bytes + 255) & ~(size_t)255;
        return p;
    };
    u16* WHP_S = (u16*)alloc(131072 * 2);
    u16* WQ_T  = (u16*)alloc(65536 * 2);
    u16* W1D_T = (u16*)alloc((size_t)HID1 * KDNN * 2);
    u16* W2D_T = (u16*)alloc((size_t)HID2 * HID1 * 2);
    u16* AQ    = (u16*)alloc((size_t)BB * FDIM * 2);
    float* QW  = (float*)alloc((size_t)BB * 128 * 4);
    u16* DNNIN = (u16*)alloc((size_t)BB * KDNN * 2);
    u16* Z     = (u16*)alloc((size_t)BB * HID1 * 2);
    float* DOUT= (float*)alloc((size_t)BB * HID2 * 4);

    prep_small<<<PREP_BLKS + BB, 256, 0, stream>>>(
        feed_table, attn_w1, dnn_w1, dnn_w2,
        WHP_S, WQ_T, W1D_T, W2D_T,
        sparse_ids, dense, feedid, emb_tables, DNNIN, AQ);
    gemm_bt<32, 64, false, false><<<dim3(BB / 32, 2), 256, 0, stream>>>(
        AQ, 512, WQ_T, 512, nullptr, QW, BB, 128, 512);
    din_fused<<<BB, 256, 0, stream>>>(
        hist_ids, feedid, feed_table, WHP_S, QW, attn_b1, attn_w2, DNNIN);
    gemm_bt<32, 64, true, true><<<dim3(BB / 32, HID1 / 64), 256, 0, stream>>>(
        DNNIN, KDNN, W1D_T, KDNN, dnn_b1, Z, BB, HID1, KDNN);
    gemm_bt<32, 64, true, false><<<dim3(BB / 32, HID2 / 64), 256, 0, stream>>>(
        Z, HID1, W2D_T, HID1, dnn_b2, DOUT, BB, HID2, HID1);
    mmoe_head<<<BB / 4, 256, 0, stream>>>(DOUT, expert_w, gate_w, out_w,
                                          out_b, out);
}

// Round 21
// 131.567 us; speedup vs baseline: 1.2557x; 1.0012x over previous
//
#include <hip/hip_runtime.h>
#include <hip/hip_bf16.h>

typedef unsigned short u16;
typedef unsigned int u32;
typedef __attribute__((ext_vector_type(8))) short short8;   // 8 bf16 for MFMA frags
typedef __attribute__((ext_vector_type(8))) u16 ushort8;
typedef __attribute__((ext_vector_type(4))) float f32x4;

// ---------- constants ----------
#define BB 2048
#define SS 8
#define DNUM 8
#define LL 50
#define EDIM 16
#define FDIM 512
#define HID1 256
#define HID2 128
#define VF 100000
#define KDNN 1216          // 1160 padded to 64-multiple
#define ROWS (BB*LL)       // 102400

// ---------- helpers ----------
__device__ inline u16 f2bf(float x) {            // HW RNE cvt (compiler packs)
    return __builtin_bit_cast(u16, __float2bfloat16(x));
}
__device__ inline float bf2f(u16 b) {
    u32 u = ((u32)b) << 16;
    return __builtin_bit_cast(float, u);
}
__device__ inline void load16_lds(const void* g, void* l) {
    __builtin_amdgcn_global_load_lds(
        (const __attribute__((address_space(1))) u32*)g,
        (__attribute__((address_space(3))) u32*)l, 16, 0, 0);
}
__device__ inline float wave_sum(float v) {
    #pragma unroll
    for (int off = 32; off > 0; off >>= 1) v += __shfl_xor(v, off, 64);
    return v;
}
__device__ inline float wave_max(float v) {
    #pragma unroll
    for (int off = 32; off > 0; off >>= 1) v = fmaxf(v, __shfl_xor(v, off, 64));
    return v;
}
__device__ inline void cvt8(const float4& a, const float4& b, ushort8& o) {
    o[0]=f2bf(a.x); o[1]=f2bf(a.y); o[2]=f2bf(a.z); o[3]=f2bf(a.w);
    o[4]=f2bf(b.x); o[5]=f2bf(b.y); o[6]=f2bf(b.z); o[7]=f2bf(b.w);
}

// ---------- K0: weight prep + per-b gather ----------
// WHP_S [128n][1024k] PRE-SWIZZLED within each 32-k tile:
//   ks = (k&~31) | ((k&31) ^ ((n&3)<<3))
#define PREP_BLKS 2112
__global__ __launch_bounds__(256) void prep_small(
    const float* __restrict__ ft,
    const float* __restrict__ w1, const float* __restrict__ dw1,
    const float* __restrict__ dw2,
    u16* __restrict__ WHP_S, u16* __restrict__ WQ_T,
    u16* __restrict__ W1D_T, u16* __restrict__ W2D_T,
    const int* __restrict__ sparse_ids, const float* __restrict__ dense,
    const int* __restrict__ feedid, const float* __restrict__ emb_tables,
    u16* __restrict__ dnn_in, u16* __restrict__ A_q)
{
    int blk = blockIdx.x, t = threadIdx.x;
    if (blk < PREP_BLKS) {
        int idx = blk * 256 + t;
        if (idx < 131072) {
            int n = idx >> 10, k = idx & 1023;
            float v;
            if (k < 512) v = w1[(512 + k) * 128 + n] - w1[(1024 + k) * 128 + n];
            else         v = w1[(1024 + k) * 128 + n];   // 1536 + (k-512)
            int ks = (k & ~31) | ((k & 31) ^ ((n & 3) << 3));
            WHP_S[n * 1024 + ks] = f2bf(v);
        } else if (idx < 196608) {
            int i = idx - 131072;
            int n = i >> 9, k = i & 511;
            WQ_T[n * 512 + k] = f2bf(w1[k * 128 + n] + w1[(1024 + k) * 128 + n]);
        } else if (idx < 507904) {
            int i = idx - 196608;
            int n = i / KDNN, k = i - n * KDNN;
            W1D_T[i] = (k < 1160) ? f2bf(dw1[k * HID1 + n]) : (u16)0;
        } else if (idx < 540672) {
            int i = idx - 507904;
            int n = i >> 8, k = i & 255;
            W2D_T[i] = f2bf(dw2[k * HID2 + n]);
        }
    } else {
        int b = blk - PREP_BLKS;
        u16* drow = dnn_in + (size_t)b * KDNN;
        if (t < 128) {
            int s = t >> 4, e = t & 15;
            int id = sparse_ids[b * SS + s];
            float v = emb_tables[(size_t)s * 1600000 + (size_t)id * EDIM + e];
            drow[t] = f2bf(v);
        } else if (t < 136) {
            drow[t] = f2bf(dense[b * DNUM + (t - 128)]);
        } else if (t < 192) {
            drow[1160 + (t - 136)] = 0;   // K padding
        }
        int fid = feedid[b];
        float2 f = *(const float2*)&ft[(size_t)fid * FDIM + t * 2];
        u16 u0 = f2bf(f.x), u1 = f2bf(f.y);
        drow[136 + t * 2] = u0;
        drow[136 + t * 2 + 1] = u1;
        A_q[(size_t)b * FDIM + t * 2] = u0;
        A_q[(size_t)b * FDIM + t * 2 + 1] = u1;
    }
}

// ---------- K2: generic bf16 MFMA GEMM, templated M/N tiles ----------
template<int BM, int BN, bool RELU, bool OUT_BF16>
__global__ __launch_bounds__(256, 4) void gemm_bt(
    const u16* __restrict__ A, int lda,
    const u16* __restrict__ BT, int ldb,
    const float* __restrict__ bias,
    void* __restrict__ Cv, int M, int N, int K)
{
    constexpr int MI = BM / 32;           // m-frags per wave
    constexpr int NJ = BN / 32;           // n-frags per wave
    __shared__ u16 As[BM * 64];
    __shared__ u16 Bs[BN * 64];
    int m0 = blockIdx.x * BM, n0 = blockIdx.y * BN;
    int tid = threadIdx.x, wave = tid >> 6, lane = tid & 63;
    int lrow = lane >> 3, lk = (lane & 7) * 8;
    f32x4 acc[MI][NJ];
    f32x4 zz = {0.f, 0.f, 0.f, 0.f};
    #pragma unroll
    for (int i = 0; i < MI; i++)
        #pragma unroll
        for (int j = 0; j < NJ; j++) acc[i][j] = zz;
    int wm = (wave >> 1) * (BM / 2), wn = (wave & 1) * (BN / 2);

    for (int kt = 0; kt < K; kt += 64) {
        #pragma unroll
        for (int j = 0; j < MI; ++j) {
            int c = wave * MI + j;
            int row = c * 8 + lrow;
            load16_lds(A + (size_t)(m0 + row) * lda + kt + lk, &As[c * 512]);
        }
        #pragma unroll
        for (int j = 0; j < NJ; ++j) {
            int c = wave * NJ + j;
            int row = c * 8 + lrow;
            load16_lds(BT + (size_t)(n0 + row) * ldb + kt + lk, &Bs[c * 512]);
        }
        __syncthreads();
        #pragma unroll
        for (int ks = 0; ks < 2; ++ks) {
            int kk = ks * 32 + (lane >> 4) * 8;
            short8 af[MI], bf[NJ];
            #pragma unroll
            for (int i = 0; i < MI; i++)
                af[i] = *(const short8*)&As[(wm + i * 16 + (lane & 15)) * 64 + kk];
            #pragma unroll
            for (int j = 0; j < NJ; j++)
                bf[j] = *(const short8*)&Bs[(wn + j * 16 + (lane & 15)) * 64 + kk];
            #pragma unroll
            for (int i = 0; i < MI; i++)
                #pragma unroll
                for (int j = 0; j < NJ; j++)
                    acc[i][j] = __builtin_amdgcn_mfma_f32_16x16x32_bf16(
                        af[i], bf[j], acc[i][j], 0, 0, 0);
        }
        __syncthreads();
    }
    #pragma unroll
    for (int i = 0; i < MI; i++) {
        #pragma unroll
        for (int j = 0; j < NJ; j++) {
            #pragma unroll
            for (int r = 0; r < 4; r++) {
                int row = m0 + wm + i * 16 + (lane >> 4) * 4 + r;
                int col = n0 + wn + j * 16 + (lane & 15);
                float v = acc[i][j][r];
                if (bias) v += bias[col];
                if (RELU) v = fmaxf(v, 0.f);
                size_t off = (size_t)row * N + col;
                if (OUT_BF16) ((u16*)Cv)[off] = f2bf(v);
                else ((float*)Cv)[off] = v;
            }
        }
    }
}

#define MFMA_BF16 __builtin_amdgcn_mfma_f32_16x16x32_bf16

// ---------- K3: DIN fused v22 — f32 q, lean VALU p-path ----------
// R20 structure; q kept in f32 LDS so p = f2bf(h_f32 * q_f32): removes the
// two bf2f unpacks per element (~40% of the compute-phase VALU) and rounds
// the product once (closer to the f32 reference).
__global__ __launch_bounds__(256, 4) void din_fused(
    const int* __restrict__ hist_ids, const int* __restrict__ feedid,
    const float* __restrict__ ft, const u16* __restrict__ WHP_S,
    const float* __restrict__ qw, const float* __restrict__ b1,
    const float* __restrict__ w2v, u16* __restrict__ dnn_in)
{
    __shared__ float Asf[2][64 * 32]; // 16 KB (dbuf f32 A, k-major chunks)
    __shared__ u16 BsH[128 * 32];     // 8 KB (swizzled content)
    __shared__ u16 BsP[128 * 32];     // 8 KB
    __shared__ float qlf[512];        // 2 KB: q row (f32)
    __shared__ float qbs[128];        // qw + b1
    __shared__ float w2s[128];
    __shared__ float sred[64 * 2];
    __shared__ float scf[64];
    __shared__ int hids[64];

    int b = blockIdx.x;
    int t = threadIdx.x, w = t >> 6, lane = t & 63;
    int fr = lane & 15, kg8 = (lane >> 4) * 8;
    int wm = (w >> 1) * 32, wn = (w & 1) * 64;
    int fid = feedid[b];

    // ---- prologue: hids, qw+b1, w2, q row (f32) — plain LDS stores ----
    if (t < 64) hids[t] = hist_ids[b * LL + (t < LL ? t : LL - 1)];
    if (t < 128) {
        qbs[t] = qw[b * 128 + t] + b1[t];
        w2s[t] = w2v[t];
    }
    {
        float2 qv = *(const float2*)&ft[(size_t)fid * FDIM + t * 2];
        qlf[t * 2] = qv.x;
        qlf[t * 2 + 1] = qv.y;
    }

    // ---- staging source pointers (rows >= LL dup row LL-1) ----
    int srow = w * 16 + fr;
    const float* a_src0 = ft + (size_t)hist_ids[b * LL + (srow < LL ? srow : LL - 1)] * FDIM
                             + (lane >> 4) * 4;
    const float* a_src1 = a_src0 + 16;
    const u16* b_src0 = WHP_S + (size_t)(w * 32 + (lane >> 2)) * 1024 + (lane & 3) * 8;
    const u16* b_src1 = b_src0 + 16 * 1024;

    f32x4 acc[2][4];
    f32x4 zz = {0.f, 0.f, 0.f, 0.f};
    #pragma unroll
    for (int i = 0; i < 2; i++)
        #pragma unroll
        for (int j = 0; j < 4; j++) acc[i][j] = zz;

    // ---- prologue staging: A(0), B(0), then A(1) LAST (stays in flight) ----
    load16_lds(a_src0,        &Asf[0][w * 512]);
    load16_lds(a_src1,        &Asf[0][w * 512 + 256]);
    load16_lds(b_src0,        &BsH[(w * 2) * 512]);
    load16_lds(b_src1,        &BsH[(w * 2 + 1) * 512]);
    load16_lds(b_src0 + 512,  &BsP[(w * 2) * 512]);
    load16_lds(b_src1 + 512,  &BsP[(w * 2 + 1) * 512]);
    load16_lds(a_src0 + 32,   &Asf[1][w * 512]);
    load16_lds(a_src1 + 32,   &Asf[1][w * 512 + 256]);
    asm volatile("s_waitcnt vmcnt(2) lgkmcnt(0)" ::: "memory");
    __builtin_amdgcn_s_barrier();

    int ws0 = wm >> 4;
    int k4a = (lane >> 4) * 2;
    int offA0 = ws0 * 512 + k4a * 64 + fr * 4;
    int offA1 = (ws0 + 1) * 512 + k4a * 64 + fr * 4;

    #pragma unroll
    for (int kt = 0; kt < 16; ++kt) {
        const int buf = kt & 1;
        const int ko = kt * 32;
        // ---- compute(kt): pure LDS/VALU/MFMA ----
        float4 h0a = *(const float4*)&Asf[buf][offA0];
        float4 h0b = *(const float4*)&Asf[buf][offA0 + 64];
        float4 h1a = *(const float4*)&Asf[buf][offA1];
        float4 h1b = *(const float4*)&Asf[buf][offA1 + 64];
        float4 q0a = *(const float4*)&qlf[ko + kg8];
        float4 q0b = *(const float4*)&qlf[ko + kg8 + 4];
        ushort8 hv0, hv1;
        cvt8(h0a, h0b, hv0);
        cvt8(h1a, h1b, hv1);
        short8 bh[4], bp[4];
        #pragma unroll
        for (int j = 0; j < 4; ++j) {
            int n = wn + j * 16 + fr;
            int kk = kg8 ^ ((n & 3) << 3);        // swizzled read
            bh[j] = *(const short8*)&BsH[n * 32 + kk];
            bp[j] = *(const short8*)&BsP[n * 32 + kk];
        }
        short8 ah0 = __builtin_bit_cast(short8, hv0);
        short8 ah1 = __builtin_bit_cast(short8, hv1);
        #pragma unroll
        for (int j = 0; j < 4; ++j) {
            acc[0][j] = MFMA_BF16(ah0, bh[j], acc[0][j], 0, 0, 0);
            acc[1][j] = MFMA_BF16(ah1, bh[j], acc[1][j], 0, 0, 0);
        }
        // p = bf16(h_f32 * q_f32): one mul + one cvt per element
        float4 p0a = make_float4(h0a.x*q0a.x, h0a.y*q0a.y, h0a.z*q0a.z, h0a.w*q0a.w);
        float4 p0b = make_float4(h0b.x*q0b.x, h0b.y*q0b.y, h0b.z*q0b.z, h0b.w*q0b.w);
        float4 p1a = make_float4(h1a.x*q0a.x, h1a.y*q0a.y, h1a.z*q0a.z, h1a.w*q0a.w);
        float4 p1b = make_float4(h1b.x*q0b.x, h1b.y*q0b.y, h1b.z*q0b.z, h1b.w*q0b.w);
        ushort8 pv0, pv1;
        cvt8(p0a, p0b, pv0);
        cvt8(p1a, p1b, pv1);
        short8 ap0 = __builtin_bit_cast(short8, pv0);
        short8 ap1 = __builtin_bit_cast(short8, pv1);
        #pragma unroll
        for (int j = 0; j < 4; ++j) {
            acc[0][j] = MFMA_BF16(ap0, bp[j], acc[0][j], 0, 0, 0);
            acc[1][j] = MFMA_BF16(ap1, bp[j], acc[1][j], 0, 0, 0);
        }
        asm volatile("s_waitcnt lgkmcnt(0)" ::: "memory");
        __builtin_amdgcn_s_barrier();
        if (kt < 15) {
            const int knB = (kt + 1) * 32;
            load16_lds(b_src0 + knB,       &BsH[(w * 2) * 512]);
            load16_lds(b_src1 + knB,       &BsH[(w * 2 + 1) * 512]);
            load16_lds(b_src0 + 512 + knB, &BsP[(w * 2) * 512]);
            load16_lds(b_src1 + 512 + knB, &BsP[(w * 2 + 1) * 512]);
            if (kt < 14) {
                const int knA = (kt + 2) * 32;
                load16_lds(a_src0 + knA, &Asf[buf][w * 512]);
                load16_lds(a_src1 + knA, &Asf[buf][w * 512 + 256]);
                asm volatile("s_waitcnt vmcnt(2)" ::: "memory");
            } else {
                asm volatile("s_waitcnt vmcnt(0)" ::: "memory");
            }
            __builtin_amdgcn_s_barrier();
        }
    }

    // ---- epilogue 1: per-row score partials ----
    #pragma unroll
    for (int i = 0; i < 2; ++i) {
        #pragma unroll
        for (int r = 0; r < 4; ++r) {
            int rl = wm + i * 16 + (lane >> 4) * 4 + r;
            float s = 0.f;
            #pragma unroll
            for (int j = 0; j < 4; ++j) {
                int col = wn + j * 16 + fr;
                float v = acc[i][j][r] + qbs[col];
                s += fmaxf(v, 0.f) * w2s[col];
            }
            s += __shfl_xor(s, 1, 64);
            s += __shfl_xor(s, 2, 64);
            s += __shfl_xor(s, 4, 64);
            s += __shfl_xor(s, 8, 64);
            if (fr == 0) sred[rl * 2 + (w & 1)] = s;
        }
    }
    __syncthreads();
    if (t < 64) scf[t] = sred[t * 2] + sred[t * 2 + 1];
    __syncthreads();
    // ---- epilogue 2: softmax over 50 ----
    if (w == 0) {
        float x = (lane < LL) ? scf[lane] : -1e30f;
        float mx = wave_max(x);
        float e = (lane < LL) ? __expf(x - mx) : 0.f;
        float s = wave_sum(e);
        scf[lane] = (lane < LL) ? e / s : 0.f;
    }
    __syncthreads();
    // ---- epilogue 3: user_interest (h rows L1/L2-hot from the gather) ----
    int d = t * 2;
    float a0 = 0.f, a1 = 0.f;
    #pragma unroll 5
    for (int l = 0; l < LL; ++l) {
        float2 hv = *(const float2*)&ft[(size_t)hids[l] * FDIM + d];
        float al = scf[l];
        a0 += al * hv.x;
        a1 += al * hv.y;
    }
    dnn_in[(size_t)b * KDNN + 648 + d] = f2bf(a0);
    dnn_in[(size_t)b * KDNN + 648 + d + 1] = f2bf(a1);
}

// ---------- K5: MMOE + task heads ----------
__global__ __launch_bounds__(256) void mmoe_head(
    const float* __restrict__ dnn_out, const float* __restrict__ expert_w,
    const float* __restrict__ gate_w, const float* __restrict__ out_w,
    const float* __restrict__ out_b, float* __restrict__ out)
{
    int wave = threadIdx.x >> 6, lane = threadIdx.x & 63;
    int b = blockIdx.x * 4 + wave;
    __shared__ float ds[4][128];
    __shared__ float eo[4][64];
    __shared__ float gt[4][32];
    ds[wave][lane] = dnn_out[b * 128 + lane];
    ds[wave][lane + 64] = dnn_out[b * 128 + 64 + lane];
    __syncthreads();
    int e = lane >> 3, o = lane & 7;
    float acc = 0.f;
    for (int k = 0; k < 128; ++k)
        acc += ds[wave][k] * expert_w[(e * 128 + k) * 8 + o];
    eo[wave][lane] = acc;
    if (lane < 32) {
        int tt = lane >> 3, ee = lane & 7;
        float g = 0.f;
        for (int k = 0; k < 128; ++k)
            g += ds[wave][k] * gate_w[(tt * 128 + k) * 8 + ee];
        float m = g;
        #pragma unroll
        for (int off = 4; off; off >>= 1) m = fmaxf(m, __shfl_xor(m, off, 8));
        float ex = __expf(g - m);
        float s = ex;
        #pragma unroll
        for (int off = 4; off; off >>= 1) s += __shfl_xor(s, off, 8);
        gt[wave][lane] = ex / s;
    }
    __syncthreads();
    if (lane < 32) {
        int tt = lane >> 3, o2 = lane & 7;
        float to = 0.f;
        #pragma unroll
        for (int ee = 0; ee < 8; ++ee)
            to += gt[wave][tt * 8 + ee] * eo[wave][ee * 8 + o2];
        float pl = to * out_w[tt * 8 + o2];
        #pragma unroll
        for (int off = 4; off; off >>= 1) pl += __shfl_xor(pl, off, 8);
        if (o2 == 0) {
            float logit = pl + out_b[tt];
            out[b * 4 + tt] = 1.f / (1.f + __expf(-logit));
        }
    }
}

// ---------- host ----------
extern "C" void kernel_launch(void* const* d_in, const int* in_sizes, int n_in,
                              void* d_out, int out_size, void* d_ws, size_t ws_size,
                              hipStream_t stream)
{
    const int*   sparse_ids = (const int*)d_in[0];
    const float* dense      = (const float*)d_in[1];
    const int*   feedid     = (const int*)d_in[2];
    const int*   hist_ids   = (const int*)d_in[3];
    const float* emb_tables = (const float*)d_in[4];
    const float* feed_table = (const float*)d_in[5];
    const float* attn_w1    = (const float*)d_in[6];
    const float* attn_b1    = (const float*)d_in[7];
    const float* attn_w2    = (const float*)d_in[8];
    const float* attn_b2    = (const float*)d_in[9];
    const float* dnn_w1     = (const float*)d_in[10];
    const float* dnn_b1     = (const float*)d_in[11];
    const float* dnn_w2     = (const float*)d_in[12];
    const float* dnn_b2     = (const float*)d_in[13];
    const float* expert_w   = (const float*)d_in[14];
    const float* gate_w     = (const float*)d_in[15];
    const float* out_w      = (const float*)d_in[16];
    const float* out_b      = (const float*)d_in[17];
    float* out = (float*)d_out;
    (void)attn_b2;   // dropped by softmax invariance

    char* ws = (char*)d_ws;
    size_t off = 0;
    auto alloc = [&](size_t bytes) {
        char* p = ws + off;
        off += (bytes + 255) & ~(size_t)255;
        return p;
    };
    u16* WHP_S = (u16*)alloc(131072 * 2);
    u16* WQ_T  = (u16*)alloc(65536 * 2);
    u16* W1D_T = (u16*)alloc((size_t)HID1 * KDNN * 2);
    u16* W2D_T = (u16*)alloc((size_t)HID2 * HID1 * 2);
    u16* AQ    = (u16*)alloc((size_t)BB * FDIM * 2);
    float* QW  = (float*)alloc((size_t)BB * 128 * 4);
    u16* DNNIN = (u16*)alloc((size_t)BB * KDNN * 2);
    u16* Z     = (u16*)alloc((size_t)BB * HID1 * 2);
    float* DOUT= (float*)alloc((size_t)BB * HID2 * 4);

    prep_small<<<PREP_BLKS + BB, 256, 0, stream>>>(
        feed_table, attn_w1, dnn_w1, dnn_w2,
        WHP_S, WQ_T, W1D_T, W2D_T,
        sparse_ids, dense, feedid, emb_tables, DNNIN, AQ);
    gemm_bt<32, 64, false, false><<<dim3(BB / 32, 2), 256, 0, stream>>>(
        AQ, 512, WQ_T, 512, nullptr, QW, BB, 128, 512);
    din_fused<<<BB, 256, 0, stream>>>(
        hist_ids, feedid, feed_table, WHP_S, QW, attn_b1, attn_w2, DNNIN);
    gemm_bt<32, 64, true, true><<<dim3(BB / 32, HID1 / 64), 256, 0, stream>>>(
        DNNIN, KDNN, W1D_T, KDNN, dnn_b1, Z, BB, HID1, KDNN);
    gemm_bt<32, 64, true, false><<<dim3(BB / 32, HID2 / 64), 256, 0, stream>>>(
        Z, HID1, W2D_T, HID1, dnn_b2, DOUT, BB, HID2, HID1);
    mmoe_head<<<BB / 4, 256, 0, stream>>>(DOUT, expert_w, gate_w, out_w,
                                          out_b, out);
}